// Round 1
// baseline (1904.332 us; speedup 1.0000x reference)
//
#include <hip/hip_runtime.h>
#include <math.h>

#define N_NODES 10000
#define N_EDGES 320000
#define ZDIM    256
#define NPAD    10112          // 79 * 128
#define PAD_J   112.0f         // NPAD - N_NODES zero-padded columns, each contributes exp(0)=1 to row sums
#define HCAP    (1u<<20)
#define HMASK   (HCAP-1u)
#define HEMPTY  0xFFFFFFFFu
#define TWO_LOG2E 2.8853900817779268f   // 2*log2(e): exp(x/0.5) = exp2(x*TWO_LOG2E)
#define LOG2E     1.4426950408889634f

__device__ __forceinline__ float wave_red_sum64(float v){
#pragma unroll
  for(int off=1; off<64; off<<=1) v += __shfl_xor(v, off, 64);
  return v;
}

// ---------- row L2 normalize (writes zero rows for padded region) ----------
__global__ void k_l2norm(const float* __restrict__ z, float* __restrict__ zn, int rows){
  int r = blockIdx.x;           // 0..NPAD-1
  int t = threadIdx.x;          // 0..255 == column
  float v = (r < rows) ? z[(size_t)r*ZDIM + t] : 0.f;
  float s = wave_red_sum64(v*v);
  __shared__ float red[4];
  int lane = t & 63, wid = t >> 6;
  if(lane==0) red[wid]=s;
  __syncthreads();
  float tot = red[0]+red[1]+red[2]+red[3];
  float scale = 1.f/fmaxf(sqrtf(tot), 1e-12f);
  zn[(size_t)r*ZDIM + t] = v*scale;
}

// ---------- out-degree (counting duplicates) ----------
__global__ void k_deg_out(const int* __restrict__ src, int* __restrict__ deg){
  int e = blockIdx.x*blockDim.x + threadIdx.x;
  if(e < N_EDGES) atomicAdd(&deg[src[e]], 1);
}
__global__ void k_inv_nb(const int* __restrict__ deg, float* __restrict__ inv_nb){
  int i = blockIdx.x*blockDim.x + threadIdx.x;
  if(i < NPAD) inv_nb[i] = (i < N_NODES) ? 1.f/sqrtf((float)deg[i] + 1.f) : 0.f;
}

// ---------- duplicate-edge multiplicity hash ----------
__global__ void k_hash_insert(const int* __restrict__ src, const int* __restrict__ dst,
                              unsigned* __restrict__ hkey, unsigned* __restrict__ hcnt){
  int e = blockIdx.x*blockDim.x + threadIdx.x;
  if(e >= N_EDGES) return;
  unsigned key = (unsigned)src[e]*10000u + (unsigned)dst[e];
  unsigned slot = (key * 2654435761u) & HMASK;
  while(true){
    unsigned old = atomicCAS(&hkey[slot], HEMPTY, key);
    if(old==HEMPTY || old==key){ atomicAdd(&hcnt[slot], 1u); break; }
    slot = (slot+1) & HMASK;
  }
}

// ---------- diagonal S_ii = z1n[i] . z2n[i] ----------
__global__ void k_diag(const float* __restrict__ z1n, const float* __restrict__ z2n,
                       float* __restrict__ sii){
  int gt = blockIdx.x*blockDim.x + threadIdx.x;
  int w = gt >> 6, lane = gt & 63;
  if(w >= N_NODES) return;
  const float4* a = (const float4*)(z1n + (size_t)w*ZDIM);
  const float4* b = (const float4*)(z2n + (size_t)w*ZDIM);
  float4 x = a[lane], y = b[lane];
  float s = x.x*y.x + x.y*y.y + x.z*y.z + x.w*y.w;
  s = wave_red_sum64(s);
  if(lane==0) sii[w] = s;
}

// ---------- streaming N^2 stats pass: per-row  d=sum(e), t1=sum(e/nb_j), t2=sum(e^2/nb_j^2) ----------
__launch_bounds__(256, 2)
__global__ void k_stats(const float* __restrict__ z1n, const float* __restrict__ z2n,
                        const float* __restrict__ inv_nb,
                        float* __restrict__ dsum, float* __restrict__ t1s, float* __restrict__ t2s){
  __shared__ float As[64][128];
  __shared__ float Bs[64][128];
  const int tid = threadIdx.x;
  const int tx = tid & 15, ty = tid >> 4;
  const int i0 = blockIdx.x * 128;
  const int nChunks = NPAD/128;                   // 79
  const int ns = gridDim.y;
  const int c0 = (nChunks *  blockIdx.y   ) / ns;
  const int c1 = (nChunks * (blockIdx.y+1)) / ns;

  float dacc[8], t1a[8], t2a[8];
#pragma unroll
  for(int r=0;r<8;r++){ dacc[r]=0.f; t1a[r]=0.f; t2a[r]=0.f; }

  for(int ch=c0; ch<c1; ++ch){
    const int j0 = ch*128;
    float acc[8][8];
#pragma unroll
    for(int r=0;r<8;r++)
#pragma unroll
      for(int c=0;c<8;c++) acc[r][c]=0.f;

    for(int kc=0; kc<ZDIM; kc+=64){
      __syncthreads();
#pragma unroll
      for(int q=0;q<8;q++){
        int lin = tid + q*256;
        int row = lin >> 4;       // 0..127
        int c4  = lin & 15;       // 0..15
        float4 va = *(const float4*)(z1n + (size_t)(i0+row)*ZDIM + kc + c4*4);
        As[c4*4+0][row]=va.x; As[c4*4+1][row]=va.y; As[c4*4+2][row]=va.z; As[c4*4+3][row]=va.w;
        float4 vb = *(const float4*)(z2n + (size_t)(j0+row)*ZDIM + kc + c4*4);
        Bs[c4*4+0][row]=vb.x; Bs[c4*4+1][row]=vb.y; Bs[c4*4+2][row]=vb.z; Bs[c4*4+3][row]=vb.w;
      }
      __syncthreads();
#pragma unroll
      for(int k=0;k<64;k++){
        float4 a0 = *(const float4*)&As[k][ty*8];
        float4 a1 = *(const float4*)&As[k][ty*8+4];
        float4 b0 = *(const float4*)&Bs[k][tx*8];
        float4 b1 = *(const float4*)&Bs[k][tx*8+4];
        float av[8]={a0.x,a0.y,a0.z,a0.w,a1.x,a1.y,a1.z,a1.w};
        float bv[8]={b0.x,b0.y,b0.z,b0.w,b1.x,b1.y,b1.z,b1.w};
#pragma unroll
        for(int r=0;r<8;r++)
#pragma unroll
          for(int c=0;c<8;c++)
            acc[r][c] = fmaf(av[r], bv[c], acc[r][c]);
      }
    }
    // epilogue: exp + row-stat accumulation (padded j: inv_nb==0, e==1 handled via PAD_J later)
    float inb[8], inb2[8];
#pragma unroll
    for(int c=0;c<8;c++){ float u = inv_nb[j0 + tx*8 + c]; inb[c]=u; inb2[c]=u*u; }
#pragma unroll
    for(int r=0;r<8;r++){
      float dr=0.f, t1r=0.f, t2r=0.f;
#pragma unroll
      for(int c=0;c<8;c++){
        float e = exp2f(acc[r][c]*TWO_LOG2E);
        dr  += e;
        t1r += e*inb[c];
        t2r += e*e*inb2[c];
      }
      dacc[r]+=dr; t1a[r]+=t1r; t2a[r]+=t2r;
    }
  }
  // reduce across tx (16 lanes sharing the same rows), then atomic per row
#pragma unroll
  for(int r=0;r<8;r++){
    float d=dacc[r], t1=t1a[r], t2=t2a[r];
#pragma unroll
    for(int off=1;off<16;off<<=1){
      d  += __shfl_xor(d,  off, 64);
      t1 += __shfl_xor(t1, off, 64);
      t2 += __shfl_xor(t2, off, 64);
    }
    if(tx==0){
      int i = i0 + ty*8 + r;
      atomicAdd(&dsum[i], d);
      atomicAdd(&t1s[i], t1);
      atomicAdd(&t2s[i], t2);
    }
  }
}

// ---------- global mean/std of P and P5 (fp64 reduce) ----------
__global__ void k_finalize(const float* __restrict__ dsum, const float* __restrict__ t1s,
                           const float* __restrict__ t2s, const float* __restrict__ inv_nb,
                           const float* __restrict__ sii, float* __restrict__ scal){
  int tid = threadIdx.x;
  double A=0,B=0,S1=0,S2=0,Snb=0,Snb2=0;
  for(int i=tid;i<N_NODES;i+=256){
    float d   = dsum[i] - PAD_J;
    float inb = inv_nb[i];
    float t1  = t1s[i], t2 = t2s[i];
    A += (double)(t1*inb/d);
    B += (double)((t2*inb*inb)/(d*d));
    float eii = exp2f(sii[i]*TWO_LOG2E);
    float ci  = fabsf(eii/d - 1.f)*inb;
    S1 += (double)ci; S2 += (double)ci*(double)ci;
    Snb += (double)inb; Snb2 += (double)inb*(double)inb;
  }
  __shared__ double red[256];
  double vals[6]={A,B,S1,S2,Snb,Snb2};
  double out[6];
  for(int v=0;v<6;v++){
    red[tid]=vals[v]; __syncthreads();
    for(int off=128;off;off>>=1){ if(tid<off) red[tid]+=red[tid+off]; __syncthreads(); }
    out[v]=red[0]; __syncthreads();
  }
  if(tid==0){
    double M = (double)N_NODES*(double)N_NODES;
    double mean  = out[0]/M;
    double var   = (out[1] - out[0]*out[0]/M)/(M-1.0);
    double sp5   = out[2]*out[4];                 // sum(P5)
    double mean5 = sp5/M;
    double var5  = (out[3]*out[5] - sp5*sp5/M)/(M-1.0);
    scal[0]=(float)mean;  scal[1]=(float)(1.0/sqrt(var));
    scal[2]=(float)mean5; scal[3]=(float)(1.0/sqrt(var5));
  }
}

// ---------- per-edge weight ----------
__global__ void k_edge_w(const int* __restrict__ src, const int* __restrict__ dst,
                         const float* __restrict__ z1n, const float* __restrict__ z2n,
                         const float* __restrict__ dsum, const float* __restrict__ inv_nb,
                         const float* __restrict__ sii, const float* __restrict__ scal,
                         const unsigned* __restrict__ hkey, const unsigned* __restrict__ hcnt,
                         float* __restrict__ ew){
  int gt = blockIdx.x*blockDim.x + threadIdx.x;
  int e = gt >> 6, lane = gt & 63;
  if(e >= N_EDGES) return;
  int s = src[e], d = dst[e];
  const float4* a = (const float4*)(z1n + (size_t)s*ZDIM);
  const float4* b = (const float4*)(z2n + (size_t)d*ZDIM);
  float4 x = a[lane], y = b[lane];
  float dot = x.x*y.x + x.y*y.y + x.z*y.z + x.w*y.w;
  dot = wave_red_sum64(dot);
  if(lane==0){
    float ds = dsum[s] - PAD_J;
    float P  = exp2f(dot*TWO_LOG2E)/ds * inv_nb[s]*inv_nb[d];
    float z  = (P - scal[0])*scal[1];
    float p12 = 1.f/(1.f + exp2f(-z*LOG2E));
    float eii = exp2f(sii[s]*TWO_LOG2E);
    float c5  = fabsf(eii/ds - 1.f)*inv_nb[s]*inv_nb[d];
    float z5  = (c5 - scal[2])*scal[3];
    float p5  = 1.f/(1.f + exp2f(-z5*LOG2E));
    unsigned key  = (unsigned)s*10000u + (unsigned)d;
    unsigned slot = (key*2654435761u) & HMASK;
    while(hkey[slot] != key) slot = (slot+1) & HMASK;
    ew[e] = 0.5f*(p5 + p12) * (float)hcnt[slot];
  }
}

// ---------- GCN degree / dinv ----------
__global__ void k_set1(float* __restrict__ p, int n){
  int i = blockIdx.x*blockDim.x + threadIdx.x;
  if(i<n) p[i]=1.f;
}
__global__ void k_degw(const int* __restrict__ dst, const float* __restrict__ ew,
                       float* __restrict__ degw){
  int e = blockIdx.x*blockDim.x + threadIdx.x;
  if(e < N_EDGES) atomicAdd(&degw[dst[e]], ew[e]);
}
__global__ void k_dinv(const float* __restrict__ degw, float* __restrict__ dinv){
  int i = blockIdx.x*blockDim.x + threadIdx.x;
  if(i < N_NODES) dinv[i] = 1.f/sqrtf(degw[i]);
}

// ---------- generic fp32 GEMM: C[M,Nc] = A[M,K] @ B[K,Nc], all row-major ----------
__launch_bounds__(256, 2)
__global__ void k_gemm(const float* __restrict__ A, const float* __restrict__ B,
                       float* __restrict__ C, int M, int K, int Nc){
  __shared__ float As[64][128];
  __shared__ float Bs[64][128];
  const int tid = threadIdx.x;
  const int tx = tid & 15, ty = tid >> 4;
  const int i0 = blockIdx.x*128, n0 = blockIdx.y*128;
  float acc[8][8];
#pragma unroll
  for(int r=0;r<8;r++)
#pragma unroll
    for(int c=0;c<8;c++) acc[r][c]=0.f;

  for(int kc=0; kc<K; kc+=64){
    __syncthreads();
#pragma unroll
    for(int q=0;q<8;q++){
      int lin = tid + q*256;
      { // A: transpose-stage
        int row = lin >> 4, c4 = lin & 15;
        int i = i0 + row;
        float4 va = make_float4(0.f,0.f,0.f,0.f);
        if(i < M) va = *(const float4*)(A + (size_t)i*K + kc + c4*4);
        As[c4*4+0][row]=va.x; As[c4*4+1][row]=va.y; As[c4*4+2][row]=va.z; As[c4*4+3][row]=va.w;
      }
      { // B: direct stage
        int row = lin >> 5, c4 = lin & 31;
        float4 vb = *(const float4*)(B + (size_t)(kc+row)*Nc + n0 + c4*4);
        *(float4*)&Bs[row][c4*4] = vb;
      }
    }
    __syncthreads();
#pragma unroll
    for(int k=0;k<64;k++){
      float4 a0 = *(const float4*)&As[k][ty*8];
      float4 a1 = *(const float4*)&As[k][ty*8+4];
      float4 b0 = *(const float4*)&Bs[k][tx*8];
      float4 b1 = *(const float4*)&Bs[k][tx*8+4];
      float av[8]={a0.x,a0.y,a0.z,a0.w,a1.x,a1.y,a1.z,a1.w};
      float bv[8]={b0.x,b0.y,b0.z,b0.w,b1.x,b1.y,b1.z,b1.w};
#pragma unroll
      for(int r=0;r<8;r++)
#pragma unroll
        for(int c=0;c<8;c++)
          acc[r][c] = fmaf(av[r], bv[c], acc[r][c]);
    }
  }
#pragma unroll
  for(int r=0;r<8;r++){
    int i = i0 + ty*8 + r;
    if(i < M){
      float4 o0 = make_float4(acc[r][0],acc[r][1],acc[r][2],acc[r][3]);
      float4 o1 = make_float4(acc[r][4],acc[r][5],acc[r][6],acc[r][7]);
      *(float4*)(C + (size_t)i*Nc + n0 + tx*8    ) = o0;
      *(float4*)(C + (size_t)i*Nc + n0 + tx*8 + 4) = o1;
    }
  }
}

// ---------- CSR by dst ----------
__global__ void k_cnt(const int* __restrict__ dst, int* __restrict__ cnt){
  int e = blockIdx.x*blockDim.x + threadIdx.x;
  if(e < N_EDGES) atomicAdd(&cnt[dst[e]], 1);
}
__global__ void k_scan(const int* __restrict__ cnt, int* __restrict__ rowptr){
  __shared__ int part[1024];
  const int PER = 10;                       // 1024*10 >= N_NODES
  int tid = threadIdx.x;
  int base = tid*PER;
  int loc[PER];
  int s=0;
#pragma unroll
  for(int q=0;q<PER;q++){ int idx=base+q; int v=(idx<N_NODES)?cnt[idx]:0; loc[q]=v; s+=v; }
  part[tid]=s; __syncthreads();
  for(int off=1; off<1024; off<<=1){
    int v = (tid>=off) ? part[tid-off] : 0;
    __syncthreads();
    part[tid] += v;
    __syncthreads();
  }
  int run = (tid>0) ? part[tid-1] : 0;
#pragma unroll
  for(int q=0;q<PER;q++){ int idx=base+q; if(idx<N_NODES) rowptr[idx]=run; run+=loc[q]; }
  if(tid==1023) rowptr[N_NODES]=part[1023];
}
__global__ void k_fill(const int* __restrict__ dst, const int* __restrict__ rowptr,
                       int* __restrict__ fill, int* __restrict__ eids){
  int e = blockIdx.x*blockDim.x + threadIdx.x;
  if(e >= N_EDGES) return;
  int d = dst[e];
  int pos = atomicAdd(&fill[d], 1);
  eids[rowptr[d]+pos] = e;
}

// ---------- GCN aggregation + bias + relu ----------
__global__ void k_agg(const float* __restrict__ hw, const float* __restrict__ bias,
                      const float* __restrict__ ew, const int* __restrict__ src,
                      const int* __restrict__ rowptr, const int* __restrict__ eids,
                      const float* __restrict__ dinv, float* __restrict__ out, int F){
  int v = blockIdx.x;
  int f = threadIdx.x;
  float dv = dinv[v];
  float acc = dv*dv*hw[(size_t)v*F + f];          // self loop, weight 1
  int b = rowptr[v], e2 = rowptr[v+1];
  for(int t=b; t<e2; ++t){
    int e = eids[t];
    int s = src[e];
    float w = dinv[s]*ew[e]*dv;
    acc = fmaf(w, hw[(size_t)s*F + f], acc);
  }
  float r = acc + bias[f];
  out[(size_t)v*F + f] = r > 0.f ? r : 0.f;
}

extern "C" void kernel_launch(void* const* d_in, const int* in_sizes, int n_in,
                              void* d_out, int out_size, void* d_ws, size_t ws_size,
                              hipStream_t stream){
  const float* x   = (const float*)d_in[0];
  const float* pz1 = (const float*)d_in[1];
  const float* pz2 = (const float*)d_in[2];
  const float* W0  = (const float*)d_in[3];
  const float* b0  = (const float*)d_in[4];
  const float* W1  = (const float*)d_in[5];
  const float* b1  = (const float*)d_in[6];
  const int*   ei  = (const int*)d_in[7];
  const int* src = ei;
  const int* dst = ei + N_EDGES;
  float* out = (float*)d_out;

  char* ws = (char*)d_ws;
  size_t off = 0;
  auto alloc = [&](size_t bytes)->char*{
    char* p = ws + off;
    off += (bytes + 255) & ~(size_t)255;
    return p;
  };

  float* z1n   = (float*)alloc((size_t)NPAD*ZDIM*4);   // later reused as hw0 / hw1
  float* z2n   = (float*)alloc((size_t)NPAD*ZDIM*4);
  float* h1    = (float*)alloc((size_t)N_NODES*512*4);
  float* ew    = (float*)alloc((size_t)N_EDGES*4);
  float* dsum  = (float*)alloc(NPAD*4);
  float* t1s   = (float*)alloc(NPAD*4);
  float* t2s   = (float*)alloc(NPAD*4);
  float* inv_nb= (float*)alloc(NPAD*4);
  float* sii   = (float*)alloc(NPAD*4);
  float* degw  = (float*)alloc(NPAD*4);
  float* dinv  = (float*)alloc(NPAD*4);
  float* scal  = (float*)alloc(256);
  int* deg     = (int*)alloc(NPAD*4);
  int* cnt     = (int*)alloc(NPAD*4);
  int* rowptr  = (int*)alloc((NPAD+1)*4);
  int* fill    = (int*)alloc(NPAD*4);
  int* eids    = (int*)alloc((size_t)N_EDGES*4);
  unsigned* hkey = (unsigned*)alloc((size_t)HCAP*4);
  unsigned* hcnt = (unsigned*)alloc((size_t)HCAP*4);
  float* hw0 = z1n;   // [N,512] fits in z1n+z2n region, used after edge weights done
  float* hw1 = z1n;   // [N,256]

  hipMemsetAsync(dsum, 0, NPAD*4, stream);
  hipMemsetAsync(t1s,  0, NPAD*4, stream);
  hipMemsetAsync(t2s,  0, NPAD*4, stream);
  hipMemsetAsync(deg,  0, NPAD*4, stream);
  hipMemsetAsync(cnt,  0, NPAD*4, stream);
  hipMemsetAsync(fill, 0, NPAD*4, stream);
  hipMemsetAsync(hkey, 0xFF, (size_t)HCAP*4, stream);
  hipMemsetAsync(hcnt, 0,    (size_t)HCAP*4, stream);

  const int EB = (N_EDGES+255)/256;

  k_l2norm<<<NPAD, 256, 0, stream>>>(pz1, z1n, N_NODES);
  k_l2norm<<<NPAD, 256, 0, stream>>>(pz2, z2n, N_NODES);
  k_deg_out<<<EB, 256, 0, stream>>>(src, deg);
  k_inv_nb<<<(NPAD+255)/256, 256, 0, stream>>>(deg, inv_nb);
  k_hash_insert<<<EB, 256, 0, stream>>>(src, dst, hkey, hcnt);
  k_diag<<<(N_NODES*64+255)/256, 256, 0, stream>>>(z1n, z2n, sii);
  k_stats<<<dim3(NPAD/128, 8), 256, 0, stream>>>(z1n, z2n, inv_nb, dsum, t1s, t2s);
  k_finalize<<<1, 256, 0, stream>>>(dsum, t1s, t2s, inv_nb, sii, scal);
  k_edge_w<<<(N_EDGES*64)/256, 256, 0, stream>>>(src, dst, z1n, z2n, dsum, inv_nb, sii, scal, hkey, hcnt, ew);

  k_set1<<<(N_NODES+255)/256, 256, 0, stream>>>(degw, N_NODES);
  k_degw<<<EB, 256, 0, stream>>>(dst, ew, degw);
  k_dinv<<<(N_NODES+255)/256, 256, 0, stream>>>(degw, dinv);

  k_cnt<<<EB, 256, 0, stream>>>(dst, cnt);
  k_scan<<<1, 1024, 0, stream>>>(cnt, rowptr);
  k_fill<<<EB, 256, 0, stream>>>(dst, rowptr, fill, eids);

  // layer 1: hw0 = x @ W0 ; h1 = relu(agg(hw0) + b0)
  k_gemm<<<dim3(79, 4), 256, 0, stream>>>(x, W0, hw0, N_NODES, 512, 512);
  k_agg<<<N_NODES, 512, 0, stream>>>(hw0, b0, ew, src, rowptr, eids, dinv, h1, 512);
  // layer 2: hw1 = h1 @ W1 ; out = relu(agg(hw1) + b1)
  k_gemm<<<dim3(79, 2), 256, 0, stream>>>(h1, W1, hw1, N_NODES, 512, 256);
  k_agg<<<N_NODES, 256, 0, stream>>>(hw1, b1, ew, src, rowptr, eids, dinv, out, 256);

  (void)in_sizes; (void)n_in; (void)out_size; (void)ws_size;
}

// Round 2
// 987.295 us; speedup vs baseline: 1.9288x; 1.9288x over previous
//
#include <hip/hip_runtime.h>
#include <math.h>

#define N_NODES 10000
#define N_EDGES 320000
#define ZDIM    256
#define NPAD    10112          // 79 * 128
#define PAD_J   112.0f         // padded cols contribute exp(0)=1 to row sums
#define HCAP    (1u<<20)
#define HMASK   (HCAP-1u)
#define HEMPTY  0xFFFFFFFFu
#define TWO_LOG2E 2.8853900817779268f   // exp(x/0.5) = exp2(x*2log2e)
#define LOG2E     1.4426950408889634f
#define YS 13                  // j-chunk splits for k_stats grid

typedef _Float16 half8 __attribute__((ext_vector_type(8)));
typedef _Float16 half4 __attribute__((ext_vector_type(4)));
typedef float f32x4 __attribute__((ext_vector_type(4)));

__device__ __forceinline__ float wave_red_sum64(float v){
#pragma unroll
  for(int off=1; off<64; off<<=1) v += __shfl_xor(v, off, 64);
  return v;
}

// ---------- row L2 normalize -> fp16 (zero pad rows) ----------
__global__ void k_l2norm_h(const float* __restrict__ z, _Float16* __restrict__ zh, int rows){
  int r = blockIdx.x;           // 0..NPAD-1
  int t = threadIdx.x;          // column
  float v = (r < rows) ? z[(size_t)r*ZDIM + t] : 0.f;
  float s = wave_red_sum64(v*v);
  __shared__ float red[4];
  int lane = t & 63, wid = t >> 6;
  if(lane==0) red[wid]=s;
  __syncthreads();
  float tot = red[0]+red[1]+red[2]+red[3];
  float scale = 1.f/fmaxf(sqrtf(tot), 1e-12f);
  zh[(size_t)r*ZDIM + t] = (_Float16)(v*scale);
}

// ---------- out-degree (counting duplicates) ----------
__global__ void k_deg_out(const int* __restrict__ src, int* __restrict__ deg){
  int e = blockIdx.x*blockDim.x + threadIdx.x;
  if(e < N_EDGES) atomicAdd(&deg[src[e]], 1);
}
__global__ void k_inv_nb(const int* __restrict__ deg, float* __restrict__ inv_nb){
  int i = blockIdx.x*blockDim.x + threadIdx.x;
  if(i < NPAD) inv_nb[i] = (i < N_NODES) ? 1.f/sqrtf((float)deg[i] + 1.f) : 0.f;
}

// ---------- duplicate-edge multiplicity hash ----------
__global__ void k_hash_insert(const int* __restrict__ src, const int* __restrict__ dst,
                              unsigned* __restrict__ hkey, unsigned* __restrict__ hcnt){
  int e = blockIdx.x*blockDim.x + threadIdx.x;
  if(e >= N_EDGES) return;
  unsigned key = (unsigned)src[e]*10000u + (unsigned)dst[e];
  unsigned slot = (key * 2654435761u) & HMASK;
  while(true){
    unsigned old = atomicCAS(&hkey[slot], HEMPTY, key);
    if(old==HEMPTY || old==key){ atomicAdd(&hcnt[slot], 1u); break; }
    slot = (slot+1) & HMASK;
  }
}

// ---------- diagonal S_ii ----------
__global__ void k_diag_h(const _Float16* __restrict__ z1h, const _Float16* __restrict__ z2h,
                         float* __restrict__ sii){
  int gt = blockIdx.x*blockDim.x + threadIdx.x;
  int n = gt >> 6, lane = gt & 63;
  if(n >= N_NODES) return;
  half4 x = *(const half4*)(z1h + (size_t)n*ZDIM + lane*4);
  half4 y = *(const half4*)(z2h + (size_t)n*ZDIM + lane*4);
  float s = (float)x[0]*(float)y[0] + (float)x[1]*(float)y[1]
          + (float)x[2]*(float)y[2] + (float)x[3]*(float)y[3];
  s = wave_red_sum64(s);
  if(lane==0) sii[n] = s;
}

// ---------- MFMA fp16 streaming stats: per-row d, t1=sum(e*inb_j), t2=sum(e^2*inb_j^2) ----------
// block 256 thr = 4 waves (2x2), tile 128(i) x 128(j), A-tile resident (128x256, swizzled),
// B single-buffered per 64-k chunk with register prefetch.
__launch_bounds__(256, 2)
__global__ void k_stats_mfma(const _Float16* __restrict__ z1h, const _Float16* __restrict__ z2h,
                             const float* __restrict__ inv_nb,
                             float* __restrict__ dsum, float* __restrict__ t1s, float* __restrict__ t2s){
  __shared__ _Float16 As[128*256];   // 64 KB, row=512B, granule-swizzled: g ^= (row&7)
  __shared__ _Float16 Bs[128*64];    // 16 KB, row=128B, granule-swizzled
  const int tid  = threadIdx.x;
  const int lane = tid & 63, w = tid >> 6;
  const int wr = w >> 1, wc = w & 1;
  const int l15 = lane & 15, l4 = lane >> 4;
  const int i0 = blockIdx.x * 128;
  const int c0 = (79 *  blockIdx.y   ) / YS;
  const int c1 = (79 * (blockIdx.y+1)) / YS;

  // stage A once (swizzled ds_write_b128; 2-way bank aliasing = free)
#pragma unroll
  for(int q=0;q<16;q++){
    int g = tid + q*256;
    int row = g >> 5, c = g & 31;
    uint4 v = *(const uint4*)(z1h + (size_t)(i0+row)*ZDIM + c*8);
    *(uint4*)((char*)As + row*512 + ((c ^ (row&7))<<4)) = v;
  }

  float dacc[4][4], t1a[4][4], t2a[4][4];
#pragma unroll
  for(int a=0;a<4;a++)
#pragma unroll
    for(int b=0;b<4;b++){ dacc[a][b]=0.f; t1a[a][b]=0.f; t2a[a][b]=0.f; }

  // prefetch first B chunk
  uint4 breg[4];
  if(c0 < c1){
#pragma unroll
    for(int q=0;q<4;q++){
      int g = tid + q*256;
      breg[q] = *(const uint4*)(z2h + (size_t)(c0*128 + (g>>3))*ZDIM + (g&7)*8);
    }
  }

  for(int ch=c0; ch<c1; ++ch){
    const int j0 = ch*128;
    float inbv[4];
#pragma unroll
    for(int nf=0;nf<4;nf++) inbv[nf] = inv_nb[j0 + wc*64 + nf*16 + l15];

    f32x4 acc[4][4];
#pragma unroll
    for(int a=0;a<4;a++)
#pragma unroll
      for(int b=0;b<4;b++) acc[a][b] = (f32x4){0.f,0.f,0.f,0.f};

#pragma unroll
    for(int kb=0; kb<4; ++kb){
      __syncthreads();                     // Bs consumers of prev chunk/kb done
#pragma unroll
      for(int q=0;q<4;q++){
        int g = tid + q*256;
        int row = g>>3, c = g&7;
        *(uint4*)((char*)Bs + row*128 + ((c ^ (row&7))<<4)) = breg[q];
      }
      // prefetch next B chunk into regs (latency hides under MFMA phase)
      {
        int nkb = kb+1, nch = ch;
        if(nkb==4){ nkb=0; nch=ch+1; }
        if(nch < c1){
#pragma unroll
          for(int q=0;q<4;q++){
            int g = tid + q*256;
            breg[q] = *(const uint4*)(z2h + (size_t)(nch*128 + (g>>3))*ZDIM + nkb*64 + (g&7)*8);
          }
        }
      }
      __syncthreads();                     // Bs staged (vmcnt/lgkm drained by barrier)
#pragma unroll
      for(int ksl=0; ksl<2; ++ksl){
        const int ks = kb*2 + ksl;
        half8 af[4], bf[4];
#pragma unroll
        for(int mf=0; mf<4; ++mf){
          int r = wr*64 + mf*16 + l15;
          af[mf] = *(const half8*)((const char*)As + r*512 + (((ks*4 + l4) ^ (r&7))<<4));
        }
#pragma unroll
        for(int nf=0; nf<4; ++nf){
          int r = wc*64 + nf*16 + l15;
          bf[nf] = *(const half8*)((const char*)Bs + r*128 + (((ksl*4 + l4) ^ (r&7))<<4));
        }
#pragma unroll
        for(int mf=0; mf<4; ++mf)
#pragma unroll
          for(int nf=0; nf<4; ++nf)
            acc[mf][nf] = __builtin_amdgcn_mfma_f32_16x16x32_f16(af[mf], bf[nf], acc[mf][nf], 0, 0, 0);
      }
    }
    // epilogue: exp + stats accumulate (C layout: col=lane&15, row=(lane>>4)*4+reg)
#pragma unroll
    for(int mf=0; mf<4; ++mf)
#pragma unroll
      for(int nf=0; nf<4; ++nf){
        float inb = inbv[nf], inb2 = inb*inb;
#pragma unroll
        for(int rg=0; rg<4; ++rg){
          float e = exp2f(acc[mf][nf][rg]*TWO_LOG2E);
          dacc[mf][rg] += e;
          t1a[mf][rg] = fmaf(e, inb, t1a[mf][rg]);
          t2a[mf][rg] = fmaf(e*e, inb2, t2a[mf][rg]);
        }
      }
  }
  // reduce across the 16 lanes sharing each row, then atomics
#pragma unroll
  for(int mf=0; mf<4; ++mf)
#pragma unroll
    for(int rg=0; rg<4; ++rg){
      float d = dacc[mf][rg], t1 = t1a[mf][rg], t2 = t2a[mf][rg];
#pragma unroll
      for(int off=1; off<16; off<<=1){
        d  += __shfl_xor(d,  off, 64);
        t1 += __shfl_xor(t1, off, 64);
        t2 += __shfl_xor(t2, off, 64);
      }
      if(l15==0){
        int i = i0 + wr*64 + mf*16 + l4*4 + rg;
        atomicAdd(&dsum[i], d);
        atomicAdd(&t1s[i], t1);
        atomicAdd(&t2s[i], t2);
      }
    }
}

// ---------- global mean/std of P and P5 (fp64 reduce) ----------
__global__ void k_finalize(const float* __restrict__ dsum, const float* __restrict__ t1s,
                           const float* __restrict__ t2s, const float* __restrict__ inv_nb,
                           const float* __restrict__ sii, float* __restrict__ scal){
  int tid = threadIdx.x;
  double A=0,B=0,S1=0,S2=0,Snb=0,Snb2=0;
  for(int i=tid;i<N_NODES;i+=256){
    float d   = dsum[i] - PAD_J;
    float inb = inv_nb[i];
    float t1  = t1s[i], t2 = t2s[i];
    A += (double)(t1*inb/d);
    B += (double)((t2*inb*inb)/(d*d));
    float eii = exp2f(sii[i]*TWO_LOG2E);
    float ci  = fabsf(eii/d - 1.f)*inb;
    S1 += (double)ci; S2 += (double)ci*(double)ci;
    Snb += (double)inb; Snb2 += (double)inb*(double)inb;
  }
  __shared__ double red[256];
  double vals[6]={A,B,S1,S2,Snb,Snb2};
  double out[6];
  for(int v=0;v<6;v++){
    red[tid]=vals[v]; __syncthreads();
    for(int off=128;off;off>>=1){ if(tid<off) red[tid]+=red[tid+off]; __syncthreads(); }
    out[v]=red[0]; __syncthreads();
  }
  if(tid==0){
    double M = (double)N_NODES*(double)N_NODES;
    double mean  = out[0]/M;
    double var   = (out[1] - out[0]*out[0]/M)/(M-1.0);
    double sp5   = out[2]*out[4];
    double mean5 = sp5/M;
    double var5  = (out[3]*out[5] - sp5*sp5/M)/(M-1.0);
    scal[0]=(float)mean;  scal[1]=(float)(1.0/sqrt(var));
    scal[2]=(float)mean5; scal[3]=(float)(1.0/sqrt(var5));
  }
}

// ---------- per-edge weight (fp16 z reads) ----------
__global__ void k_edge_w(const int* __restrict__ src, const int* __restrict__ dst,
                         const _Float16* __restrict__ z1h, const _Float16* __restrict__ z2h,
                         const float* __restrict__ dsum, const float* __restrict__ inv_nb,
                         const float* __restrict__ sii, const float* __restrict__ scal,
                         const unsigned* __restrict__ hkey, const unsigned* __restrict__ hcnt,
                         float* __restrict__ ew){
  int gt = blockIdx.x*blockDim.x + threadIdx.x;
  int e = gt >> 6, lane = gt & 63;
  if(e >= N_EDGES) return;
  int s = src[e], d = dst[e];
  half4 x = *(const half4*)(z1h + (size_t)s*ZDIM + lane*4);
  half4 y = *(const half4*)(z2h + (size_t)d*ZDIM + lane*4);
  float dot = (float)x[0]*(float)y[0] + (float)x[1]*(float)y[1]
            + (float)x[2]*(float)y[2] + (float)x[3]*(float)y[3];
  dot = wave_red_sum64(dot);
  if(lane==0){
    float ds = dsum[s] - PAD_J;
    float P  = exp2f(dot*TWO_LOG2E)/ds * inv_nb[s]*inv_nb[d];
    float z  = (P - scal[0])*scal[1];
    float p12 = 1.f/(1.f + exp2f(-z*LOG2E));
    float eii = exp2f(sii[s]*TWO_LOG2E);
    float c5  = fabsf(eii/ds - 1.f)*inv_nb[s]*inv_nb[d];
    float z5  = (c5 - scal[2])*scal[3];
    float p5  = 1.f/(1.f + exp2f(-z5*LOG2E));
    unsigned key  = (unsigned)s*10000u + (unsigned)d;
    unsigned slot = (key*2654435761u) & HMASK;
    while(hkey[slot] != key) slot = (slot+1) & HMASK;
    ew[e] = 0.5f*(p5 + p12) * (float)hcnt[slot];
  }
}

// ---------- GCN degree / dinv ----------
__global__ void k_set1(float* __restrict__ p, int n){
  int i = blockIdx.x*blockDim.x + threadIdx.x;
  if(i<n) p[i]=1.f;
}
__global__ void k_degw(const int* __restrict__ dst, const float* __restrict__ ew,
                       float* __restrict__ degw){
  int e = blockIdx.x*blockDim.x + threadIdx.x;
  if(e < N_EDGES) atomicAdd(&degw[dst[e]], ew[e]);
}
__global__ void k_dinv(const float* __restrict__ degw, float* __restrict__ dinv){
  int i = blockIdx.x*blockDim.x + threadIdx.x;
  if(i < N_NODES) dinv[i] = 1.f/sqrtf(degw[i]);
}

// ---------- fp32 GEMM: C[M,Nc](fp16) = A[M,K](f32) @ B[K,Nc](f32) ----------
__launch_bounds__(256, 2)
__global__ void k_gemm(const float* __restrict__ A, const float* __restrict__ B,
                       _Float16* __restrict__ C, int M, int K, int Nc){
  __shared__ float As[64][128];
  __shared__ float Bs[64][128];
  const int tid = threadIdx.x;
  const int tx = tid & 15, ty = tid >> 4;
  const int i0 = blockIdx.x*128, n0 = blockIdx.y*128;
  float acc[8][8];
#pragma unroll
  for(int r=0;r<8;r++)
#pragma unroll
    for(int c=0;c<8;c++) acc[r][c]=0.f;

  for(int kc=0; kc<K; kc+=64){
    __syncthreads();
#pragma unroll
    for(int q=0;q<8;q++){
      int lin = tid + q*256;
      {
        int row = lin >> 4, c4 = lin & 15;
        int i = i0 + row;
        float4 va = make_float4(0.f,0.f,0.f,0.f);
        if(i < M) va = *(const float4*)(A + (size_t)i*K + kc + c4*4);
        As[c4*4+0][row]=va.x; As[c4*4+1][row]=va.y; As[c4*4+2][row]=va.z; As[c4*4+3][row]=va.w;
      }
      {
        int row = lin >> 5, c4 = lin & 31;
        float4 vb = *(const float4*)(B + (size_t)(kc+row)*Nc + n0 + c4*4);
        *(float4*)&Bs[row][c4*4] = vb;
      }
    }
    __syncthreads();
#pragma unroll
    for(int k=0;k<64;k++){
      float4 a0 = *(const float4*)&As[k][ty*8];
      float4 a1 = *(const float4*)&As[k][ty*8+4];
      float4 b0 = *(const float4*)&Bs[k][tx*8];
      float4 b1 = *(const float4*)&Bs[k][tx*8+4];
      float av[8]={a0.x,a0.y,a0.z,a0.w,a1.x,a1.y,a1.z,a1.w};
      float bv[8]={b0.x,b0.y,b0.z,b0.w,b1.x,b1.y,b1.z,b1.w};
#pragma unroll
      for(int r=0;r<8;r++)
#pragma unroll
        for(int c=0;c<8;c++)
          acc[r][c] = fmaf(av[r], bv[c], acc[r][c]);
    }
  }
#pragma unroll
  for(int r=0;r<8;r++){
    int i = i0 + ty*8 + r;
    if(i < M){
      half8 o;
#pragma unroll
      for(int c=0;c<8;c++) o[c] = (_Float16)acc[r][c];
      *(half8*)(C + (size_t)i*Nc + n0 + tx*8) = o;
    }
  }
}

// ---------- CSR by dst ----------
__global__ void k_cnt(const int* __restrict__ dst, int* __restrict__ cnt){
  int e = blockIdx.x*blockDim.x + threadIdx.x;
  if(e < N_EDGES) atomicAdd(&cnt[dst[e]], 1);
}
__global__ void k_scan(const int* __restrict__ cnt, int* __restrict__ rowptr){
  __shared__ int part[1024];
  const int PER = 10;
  int tid = threadIdx.x;
  int base = tid*PER;
  int loc[PER];
  int s=0;
#pragma unroll
  for(int q=0;q<PER;q++){ int idx=base+q; int v=(idx<N_NODES)?cnt[idx]:0; loc[q]=v; s+=v; }
  part[tid]=s; __syncthreads();
  for(int off=1; off<1024; off<<=1){
    int v = (tid>=off) ? part[tid-off] : 0;
    __syncthreads();
    part[tid] += v;
    __syncthreads();
  }
  int run = (tid>0) ? part[tid-1] : 0;
#pragma unroll
  for(int q=0;q<PER;q++){ int idx=base+q; if(idx<N_NODES) rowptr[idx]=run; run+=loc[q]; }
  if(tid==1023) rowptr[N_NODES]=part[1023];
}
__global__ void k_fill(const int* __restrict__ dst, const int* __restrict__ rowptr,
                       int* __restrict__ fill, int* __restrict__ eids){
  int e = blockIdx.x*blockDim.x + threadIdx.x;
  if(e >= N_EDGES) return;
  int d = dst[e];
  int pos = atomicAdd(&fill[d], 1);
  eids[rowptr[d]+pos] = e;
}

// ---------- GCN aggregation + bias + relu (fp16 hw gathers) ----------
__global__ void k_agg(const _Float16* __restrict__ hw, const float* __restrict__ bias,
                      const float* __restrict__ ew, const int* __restrict__ src,
                      const int* __restrict__ rowptr, const int* __restrict__ eids,
                      const float* __restrict__ dinv, float* __restrict__ out, int F){
  int v = blockIdx.x;
  int f = threadIdx.x;
  float dv = dinv[v];
  float acc = dv*dv*(float)hw[(size_t)v*F + f];     // self loop, weight 1
  int b = rowptr[v], e2 = rowptr[v+1];
  for(int t=b; t<e2; ++t){
    int e = eids[t];
    int s = src[e];
    float wgt = dinv[s]*ew[e]*dv;
    acc = fmaf(wgt, (float)hw[(size_t)s*F + f], acc);
  }
  float r = acc + bias[f];
  out[(size_t)v*F + f] = r > 0.f ? r : 0.f;
}

extern "C" void kernel_launch(void* const* d_in, const int* in_sizes, int n_in,
                              void* d_out, int out_size, void* d_ws, size_t ws_size,
                              hipStream_t stream){
  const float* x   = (const float*)d_in[0];
  const float* pz1 = (const float*)d_in[1];
  const float* pz2 = (const float*)d_in[2];
  const float* W0  = (const float*)d_in[3];
  const float* b0  = (const float*)d_in[4];
  const float* W1  = (const float*)d_in[5];
  const float* b1  = (const float*)d_in[6];
  const int*   ei  = (const int*)d_in[7];
  const int* src = ei;
  const int* dst = ei + N_EDGES;
  float* out = (float*)d_out;

  char* ws = (char*)d_ws;
  size_t off = 0;
  auto alloc = [&](size_t bytes)->char*{
    char* p = ws + off;
    off += (bytes + 255) & ~(size_t)255;
    return p;
  };

  _Float16* z1h  = (_Float16*)alloc((size_t)NPAD*ZDIM*2);   // 5.18 MB; reused as hw1h later
  _Float16* z2h  = (_Float16*)alloc((size_t)NPAD*ZDIM*2);   // 5.18 MB
  float* h1      = (float*)alloc((size_t)N_NODES*512*4);    // 20.5 MB
  _Float16* hw0h = (_Float16*)alloc((size_t)N_NODES*512*2); // 10.2 MB
  float* ew      = (float*)alloc((size_t)N_EDGES*4);
  float* dsum    = (float*)alloc(NPAD*4);
  float* t1s     = (float*)alloc(NPAD*4);
  float* t2s     = (float*)alloc(NPAD*4);
  float* inv_nb  = (float*)alloc(NPAD*4);
  float* sii     = (float*)alloc(NPAD*4);
  float* degw    = (float*)alloc(NPAD*4);
  float* dinv    = (float*)alloc(NPAD*4);
  float* scal    = (float*)alloc(256);
  int* deg       = (int*)alloc(NPAD*4);
  int* cnt       = (int*)alloc(NPAD*4);
  int* rowptr    = (int*)alloc((NPAD+1)*4);
  int* fill      = (int*)alloc(NPAD*4);
  int* eids      = (int*)alloc((size_t)N_EDGES*4);
  unsigned* hkey = (unsigned*)alloc((size_t)HCAP*4);
  unsigned* hcnt = (unsigned*)alloc((size_t)HCAP*4);
  _Float16* hw1h = z1h;     // [N,256] fp16, z1h dead after k_edge_w

  hipMemsetAsync(dsum, 0, NPAD*4, stream);
  hipMemsetAsync(t1s,  0, NPAD*4, stream);
  hipMemsetAsync(t2s,  0, NPAD*4, stream);
  hipMemsetAsync(deg,  0, NPAD*4, stream);
  hipMemsetAsync(cnt,  0, NPAD*4, stream);
  hipMemsetAsync(fill, 0, NPAD*4, stream);
  hipMemsetAsync(hkey, 0xFF, (size_t)HCAP*4, stream);
  hipMemsetAsync(hcnt, 0,    (size_t)HCAP*4, stream);

  const int EB = (N_EDGES+255)/256;

  k_l2norm_h<<<NPAD, 256, 0, stream>>>(pz1, z1h, N_NODES);
  k_l2norm_h<<<NPAD, 256, 0, stream>>>(pz2, z2h, N_NODES);
  k_deg_out<<<EB, 256, 0, stream>>>(src, deg);
  k_inv_nb<<<(NPAD+255)/256, 256, 0, stream>>>(deg, inv_nb);
  k_hash_insert<<<EB, 256, 0, stream>>>(src, dst, hkey, hcnt);
  k_diag_h<<<(N_NODES*64+255)/256, 256, 0, stream>>>(z1h, z2h, sii);
  k_stats_mfma<<<dim3(79, YS), 256, 0, stream>>>(z1h, z2h, inv_nb, dsum, t1s, t2s);
  k_finalize<<<1, 256, 0, stream>>>(dsum, t1s, t2s, inv_nb, sii, scal);
  k_edge_w<<<(N_EDGES*64)/256, 256, 0, stream>>>(src, dst, z1h, z2h, dsum, inv_nb, sii, scal, hkey, hcnt, ew);

  k_set1<<<(N_NODES+255)/256, 256, 0, stream>>>(degw, N_NODES);
  k_degw<<<EB, 256, 0, stream>>>(dst, ew, degw);
  k_dinv<<<(N_NODES+255)/256, 256, 0, stream>>>(degw, dinv);

  k_cnt<<<EB, 256, 0, stream>>>(dst, cnt);
  k_scan<<<1, 1024, 0, stream>>>(cnt, rowptr);
  k_fill<<<EB, 256, 0, stream>>>(dst, rowptr, fill, eids);

  // layer 1: hw0h = fp16(x @ W0); h1 = relu(agg(hw0h) + b0)
  k_gemm<<<dim3(79, 4), 256, 0, stream>>>(x, W0, hw0h, N_NODES, 512, 512);
  k_agg<<<N_NODES, 512, 0, stream>>>(hw0h, b0, ew, src, rowptr, eids, dinv, h1, 512);
  // layer 2: hw1h = fp16(h1 @ W1); out = relu(agg(hw1h) + b1)   (hw1h overwrites z1h: dead)
  k_gemm<<<dim3(79, 2), 256, 0, stream>>>(h1, W1, hw1h, N_NODES, 512, 256);
  k_agg<<<N_NODES, 256, 0, stream>>>(hw1h, b1, ew, src, rowptr, eids, dinv, out, 256);

  (void)in_sizes; (void)n_in; (void)out_size; (void)ws_size;
}

// Round 3
// 584.624 us; speedup vs baseline: 3.2574x; 1.6888x over previous
//
#include <hip/hip_runtime.h>
#include <math.h>

#define N_NODES 10000
#define N_EDGES 320000
#define ZDIM    256
#define NPAD    10112          // 79 * 128
#define PAD_J   112.0f         // padded cols contribute exp(0)=1 to row sums
#define HCAP    (1u<<19)
#define HMASK   (HCAP-1u)
#define HEMPTY  0xFFFFFFFFu
#define TWO_LOG2E 2.8853900817779268f   // exp(x/0.5) = exp2(x*2log2e)
#define LOG2E     1.4426950408889634f
#define YS 13                  // j-chunk splits for k_stats grid

typedef _Float16 half8 __attribute__((ext_vector_type(8)));
typedef _Float16 half4 __attribute__((ext_vector_type(4)));
typedef float f32x4 __attribute__((ext_vector_type(4)));

__device__ __forceinline__ float wave_red_sum64(float v){
#pragma unroll
  for(int off=1; off<64; off<<=1) v += __shfl_xor(v, off, 64);
  return v;
}

// ---------- row L2 normalize -> fp16 (zero pad rows) ----------
__global__ void k_l2norm_h(const float* __restrict__ z, _Float16* __restrict__ zh, int rows){
  int r = blockIdx.x;
  int t = threadIdx.x;
  float v = (r < rows) ? z[(size_t)r*ZDIM + t] : 0.f;
  float s = wave_red_sum64(v*v);
  __shared__ float red[4];
  int lane = t & 63, wid = t >> 6;
  if(lane==0) red[wid]=s;
  __syncthreads();
  float tot = red[0]+red[1]+red[2]+red[3];
  float scale = 1.f/fmaxf(sqrtf(tot), 1e-12f);
  zh[(size_t)r*ZDIM + t] = (_Float16)(v*scale);
}

// ---------- out-degree (counting duplicates) ----------
__global__ void k_deg_out(const int* __restrict__ src, int* __restrict__ deg){
  int e = blockIdx.x*blockDim.x + threadIdx.x;
  if(e < N_EDGES) atomicAdd(&deg[src[e]], 1);
}
__global__ void k_inv_nb(const int* __restrict__ deg, float* __restrict__ inv_nb){
  int i = blockIdx.x*blockDim.x + threadIdx.x;
  if(i < NPAD) inv_nb[i] = (i < N_NODES) ? 1.f/sqrtf((float)deg[i] + 1.f) : 0.f;
}

// ---------- duplicate-edge multiplicity hash ----------
__global__ void k_hash_insert(const int* __restrict__ src, const int* __restrict__ dst,
                              unsigned* __restrict__ hkey, unsigned* __restrict__ hcnt){
  int e = blockIdx.x*blockDim.x + threadIdx.x;
  if(e >= N_EDGES) return;
  unsigned key = (unsigned)src[e]*10000u + (unsigned)dst[e];
  unsigned slot = (key * 2654435761u) & HMASK;
  while(true){
    unsigned old = atomicCAS(&hkey[slot], HEMPTY, key);
    if(old==HEMPTY || old==key){ atomicAdd(&hcnt[slot], 1u); break; }
    slot = (slot+1) & HMASK;
  }
}

// ---------- diagonal S_ii ----------
__global__ void k_diag_h(const _Float16* __restrict__ z1h, const _Float16* __restrict__ z2h,
                         float* __restrict__ sii){
  int gt = blockIdx.x*blockDim.x + threadIdx.x;
  int n = gt >> 6, lane = gt & 63;
  if(n >= N_NODES) return;
  half4 x = *(const half4*)(z1h + (size_t)n*ZDIM + lane*4);
  half4 y = *(const half4*)(z2h + (size_t)n*ZDIM + lane*4);
  float s = (float)x[0]*(float)y[0] + (float)x[1]*(float)y[1]
          + (float)x[2]*(float)y[2] + (float)x[3]*(float)y[3];
  s = wave_red_sum64(s);
  if(lane==0) sii[n] = s;
}

// ---------- MFMA fp16 streaming stats ----------
__launch_bounds__(256, 2)
__global__ void k_stats_mfma(const _Float16* __restrict__ z1h, const _Float16* __restrict__ z2h,
                             const float* __restrict__ inv_nb,
                             float* __restrict__ dsum, float* __restrict__ t1s, float* __restrict__ t2s){
  __shared__ _Float16 As[128*256];   // 64 KB, row=512B, granule-swizzled
  __shared__ _Float16 Bs[128*64];    // 16 KB
  const int tid  = threadIdx.x;
  const int lane = tid & 63, w = tid >> 6;
  const int wr = w >> 1, wc = w & 1;
  const int l15 = lane & 15, l4 = lane >> 4;
  const int i0 = blockIdx.x * 128;
  const int c0 = (79 *  blockIdx.y   ) / YS;
  const int c1 = (79 * (blockIdx.y+1)) / YS;

#pragma unroll
  for(int q=0;q<16;q++){
    int g = tid + q*256;
    int row = g >> 5, c = g & 31;
    uint4 v = *(const uint4*)(z1h + (size_t)(i0+row)*ZDIM + c*8);
    *(uint4*)((char*)As + row*512 + ((c ^ (row&7))<<4)) = v;
  }

  float dacc[4][4], t1a[4][4], t2a[4][4];
#pragma unroll
  for(int a=0;a<4;a++)
#pragma unroll
    for(int b=0;b<4;b++){ dacc[a][b]=0.f; t1a[a][b]=0.f; t2a[a][b]=0.f; }

  uint4 breg[4];
  if(c0 < c1){
#pragma unroll
    for(int q=0;q<4;q++){
      int g = tid + q*256;
      breg[q] = *(const uint4*)(z2h + (size_t)(c0*128 + (g>>3))*ZDIM + (g&7)*8);
    }
  }

  for(int ch=c0; ch<c1; ++ch){
    const int j0 = ch*128;
    float inbv[4];
#pragma unroll
    for(int nf=0;nf<4;nf++) inbv[nf] = inv_nb[j0 + wc*64 + nf*16 + l15];

    f32x4 acc[4][4];
#pragma unroll
    for(int a=0;a<4;a++)
#pragma unroll
      for(int b=0;b<4;b++) acc[a][b] = (f32x4){0.f,0.f,0.f,0.f};

#pragma unroll
    for(int kb=0; kb<4; ++kb){
      __syncthreads();
#pragma unroll
      for(int q=0;q<4;q++){
        int g = tid + q*256;
        int row = g>>3, c = g&7;
        *(uint4*)((char*)Bs + row*128 + ((c ^ (row&7))<<4)) = breg[q];
      }
      {
        int nkb = kb+1, nch = ch;
        if(nkb==4){ nkb=0; nch=ch+1; }
        if(nch < c1){
#pragma unroll
          for(int q=0;q<4;q++){
            int g = tid + q*256;
            breg[q] = *(const uint4*)(z2h + (size_t)(nch*128 + (g>>3))*ZDIM + nkb*64 + (g&7)*8);
          }
        }
      }
      __syncthreads();
#pragma unroll
      for(int ksl=0; ksl<2; ++ksl){
        const int ks = kb*2 + ksl;
        half8 af[4], bf[4];
#pragma unroll
        for(int mf=0; mf<4; ++mf){
          int r = wr*64 + mf*16 + l15;
          af[mf] = *(const half8*)((const char*)As + r*512 + (((ks*4 + l4) ^ (r&7))<<4));
        }
#pragma unroll
        for(int nf=0; nf<4; ++nf){
          int r = wc*64 + nf*16 + l15;
          bf[nf] = *(const half8*)((const char*)Bs + r*128 + (((ksl*4 + l4) ^ (r&7))<<4));
        }
#pragma unroll
        for(int mf=0; mf<4; ++mf)
#pragma unroll
          for(int nf=0; nf<4; ++nf)
            acc[mf][nf] = __builtin_amdgcn_mfma_f32_16x16x32_f16(af[mf], bf[nf], acc[mf][nf], 0, 0, 0);
      }
    }
#pragma unroll
    for(int mf=0; mf<4; ++mf)
#pragma unroll
      for(int nf=0; nf<4; ++nf){
        float inb = inbv[nf], inb2 = inb*inb;
#pragma unroll
        for(int rg=0; rg<4; ++rg){
          float e = exp2f(acc[mf][nf][rg]*TWO_LOG2E);
          dacc[mf][rg] += e;
          t1a[mf][rg] = fmaf(e, inb, t1a[mf][rg]);
          t2a[mf][rg] = fmaf(e*e, inb2, t2a[mf][rg]);
        }
      }
  }
#pragma unroll
  for(int mf=0; mf<4; ++mf)
#pragma unroll
    for(int rg=0; rg<4; ++rg){
      float d = dacc[mf][rg], t1 = t1a[mf][rg], t2 = t2a[mf][rg];
#pragma unroll
      for(int off=1; off<16; off<<=1){
        d  += __shfl_xor(d,  off, 64);
        t1 += __shfl_xor(t1, off, 64);
        t2 += __shfl_xor(t2, off, 64);
      }
      if(l15==0){
        int i = i0 + wr*64 + mf*16 + l4*4 + rg;
        atomicAdd(&dsum[i], d);
        atomicAdd(&t1s[i], t1);
        atomicAdd(&t2s[i], t2);
      }
    }
}

// ---------- global mean/std of P and P5 (fp64 reduce) ----------
__global__ void k_finalize(const float* __restrict__ dsum, const float* __restrict__ t1s,
                           const float* __restrict__ t2s, const float* __restrict__ inv_nb,
                           const float* __restrict__ sii, float* __restrict__ scal){
  int tid = threadIdx.x;
  double A=0,B=0,S1=0,S2=0,Snb=0,Snb2=0;
  for(int i=tid;i<N_NODES;i+=256){
    float d   = dsum[i] - PAD_J;
    float inb = inv_nb[i];
    float t1  = t1s[i], t2 = t2s[i];
    A += (double)(t1*inb/d);
    B += (double)((t2*inb*inb)/(d*d));
    float eii = exp2f(sii[i]*TWO_LOG2E);
    float ci  = fabsf(eii/d - 1.f)*inb;
    S1 += (double)ci; S2 += (double)ci*(double)ci;
    Snb += (double)inb; Snb2 += (double)inb*(double)inb;
  }
  __shared__ double red[256];
  double vals[6]={A,B,S1,S2,Snb,Snb2};
  double out[6];
  for(int v=0;v<6;v++){
    red[tid]=vals[v]; __syncthreads();
    for(int off=128;off;off>>=1){ if(tid<off) red[tid]+=red[tid+off]; __syncthreads(); }
    out[v]=red[0]; __syncthreads();
  }
  if(tid==0){
    double M = (double)N_NODES*(double)N_NODES;
    double mean  = out[0]/M;
    double var   = (out[1] - out[0]*out[0]/M)/(M-1.0);
    double sp5   = out[2]*out[4];
    double mean5 = sp5/M;
    double var5  = (out[3]*out[5] - sp5*sp5/M)/(M-1.0);
    scal[0]=(float)mean;  scal[1]=(float)(1.0/sqrt(var));
    scal[2]=(float)mean5; scal[3]=(float)(1.0/sqrt(var5));
  }
}

// ---------- per-edge weight: 16 lanes per edge ----------
__global__ void k_edge_w(const int* __restrict__ src, const int* __restrict__ dst,
                         const _Float16* __restrict__ z1h, const _Float16* __restrict__ z2h,
                         const float* __restrict__ dsum, const float* __restrict__ inv_nb,
                         const float* __restrict__ sii, const float* __restrict__ scal,
                         const unsigned* __restrict__ hkey, const unsigned* __restrict__ hcnt,
                         float* __restrict__ ew){
  int gt = blockIdx.x*blockDim.x + threadIdx.x;
  int e = gt >> 4, l = gt & 15;
  if(e >= N_EDGES) return;
  int s = src[e], d = dst[e];
  half8 x0 = *(const half8*)(z1h + (size_t)s*ZDIM + l*16);
  half8 x1 = *(const half8*)(z1h + (size_t)s*ZDIM + l*16 + 8);
  half8 y0 = *(const half8*)(z2h + (size_t)d*ZDIM + l*16);
  half8 y1 = *(const half8*)(z2h + (size_t)d*ZDIM + l*16 + 8);
  float dot = 0.f;
#pragma unroll
  for(int q=0;q<8;q++) dot = fmaf((float)x0[q], (float)y0[q], dot);
#pragma unroll
  for(int q=0;q<8;q++) dot = fmaf((float)x1[q], (float)y1[q], dot);
#pragma unroll
  for(int off=1; off<16; off<<=1) dot += __shfl_xor(dot, off, 64);
  if(l==0){
    float ds = dsum[s] - PAD_J;
    float P  = exp2f(dot*TWO_LOG2E)/ds * inv_nb[s]*inv_nb[d];
    float z  = (P - scal[0])*scal[1];
    float p12 = 1.f/(1.f + exp2f(-z*LOG2E));
    float eii = exp2f(sii[s]*TWO_LOG2E);
    float c5  = fabsf(eii/ds - 1.f)*inv_nb[s]*inv_nb[d];
    float z5  = (c5 - scal[2])*scal[3];
    float p5  = 1.f/(1.f + exp2f(-z5*LOG2E));
    unsigned key  = (unsigned)s*10000u + (unsigned)d;
    unsigned slot = (key*2654435761u) & HMASK;
    while(hkey[slot] != key) slot = (slot+1) & HMASK;
    ew[e] = 0.5f*(p5 + p12) * (float)hcnt[slot];
  }
}

// ---------- GCN degree / dinv ----------
__global__ void k_set1(float* __restrict__ p, int n){
  int i = blockIdx.x*blockDim.x + threadIdx.x;
  if(i<n) p[i]=1.f;
}
__global__ void k_degw(const int* __restrict__ dst, const float* __restrict__ ew,
                       float* __restrict__ degw){
  int e = blockIdx.x*blockDim.x + threadIdx.x;
  if(e < N_EDGES) atomicAdd(&degw[dst[e]], ew[e]);
}
__global__ void k_dinv(const float* __restrict__ degw, float* __restrict__ dinv){
  int i = blockIdx.x*blockDim.x + threadIdx.x;
  if(i < N_NODES) dinv[i] = 1.f/sqrtf(degw[i]);
}

// ---------- cast fp32 -> fp16 with zero row padding ----------
__global__ void k_cast_pad(const float* __restrict__ A, _Float16* __restrict__ Ah, int M, int K){
  size_t t = (size_t)blockIdx.x*256 + threadIdx.x;
  size_t total = (size_t)NPAD*K/8;
  if(t >= total) return;
  size_t base = t*8;
  int row = (int)(base / (size_t)K);
  half8 o;
  if(row < M){
    float4 v0 = *(const float4*)(A + base);
    float4 v1 = *(const float4*)(A + base + 4);
    o[0]=(_Float16)v0.x; o[1]=(_Float16)v0.y; o[2]=(_Float16)v0.z; o[3]=(_Float16)v0.w;
    o[4]=(_Float16)v1.x; o[5]=(_Float16)v1.y; o[6]=(_Float16)v1.z; o[7]=(_Float16)v1.w;
  } else {
#pragma unroll
    for(int q=0;q<8;q++) o[q]=(_Float16)0.f;
  }
  *(half8*)(Ah + base) = o;
}

// ---------- transpose + cast: WT[n][k] = (fp16)W[k][n] ----------
__global__ void k_transpose_h(const float* __restrict__ W, _Float16* __restrict__ WT, int K, int N){
  __shared__ float t[32][33];
  int bx = blockIdx.x*32, by = blockIdx.y*32;   // bx: n-base, by: k-base
  int tx = threadIdx.x, ty = threadIdx.y;       // 32 x 8
  for(int r=ty; r<32; r+=8) t[r][tx] = W[(size_t)(by+r)*N + bx+tx];
  __syncthreads();
  for(int r=ty; r<32; r+=8) WT[(size_t)(bx+r)*K + by+tx] = (_Float16)t[tx][r];
}

// ---------- MFMA fp16 GEMM: C[NPAD,Nc](fp16) = Ah[NPAD,K] @ BT[Nc,K]^T ----------
__launch_bounds__(256, 2)
__global__ void k_gemm_h(const _Float16* __restrict__ Ah, const _Float16* __restrict__ BT,
                         _Float16* __restrict__ C, int K, int Nc){
  __shared__ _Float16 As[128*64];    // 16 KB, row=128B, granule-swizzled
  __shared__ _Float16 Bs[128*64];    // 16 KB
  const int tid  = threadIdx.x;
  const int lane = tid & 63, w = tid >> 6;
  const int wr = w >> 1, wc = w & 1;
  const int l15 = lane & 15, l4 = lane >> 4;
  const int i0 = blockIdx.x * 128;
  const int n0 = blockIdx.y * 128;

  f32x4 acc[4][4];
#pragma unroll
  for(int a=0;a<4;a++)
#pragma unroll
    for(int b=0;b<4;b++) acc[a][b] = (f32x4){0.f,0.f,0.f,0.f};

  uint4 areg[4], brg[4];
#pragma unroll
  for(int q=0;q<4;q++){
    int g = tid + q*256;
    areg[q] = *(const uint4*)(Ah + (size_t)(i0 + (g>>3))*K + (g&7)*8);
    brg[q]  = *(const uint4*)(BT + (size_t)(n0 + (g>>3))*K + (g&7)*8);
  }

  for(int kc=0; kc<K; kc+=64){
    __syncthreads();
#pragma unroll
    for(int q=0;q<4;q++){
      int g = tid + q*256;
      int row = g>>3, c = g&7;
      *(uint4*)((char*)As + row*128 + ((c ^ (row&7))<<4)) = areg[q];
      *(uint4*)((char*)Bs + row*128 + ((c ^ (row&7))<<4)) = brg[q];
    }
    if(kc + 64 < K){
#pragma unroll
      for(int q=0;q<4;q++){
        int g = tid + q*256;
        areg[q] = *(const uint4*)(Ah + (size_t)(i0 + (g>>3))*K + kc + 64 + (g&7)*8);
        brg[q]  = *(const uint4*)(BT + (size_t)(n0 + (g>>3))*K + kc + 64 + (g&7)*8);
      }
    }
    __syncthreads();
#pragma unroll
    for(int ksl=0; ksl<2; ++ksl){
      half8 af[4], bf[4];
#pragma unroll
      for(int mf=0; mf<4; ++mf){
        int r = wr*64 + mf*16 + l15;
        af[mf] = *(const half8*)((const char*)As + r*128 + (((ksl*4 + l4) ^ (r&7))<<4));
      }
#pragma unroll
      for(int nf=0; nf<4; ++nf){
        int r = wc*64 + nf*16 + l15;
        bf[nf] = *(const half8*)((const char*)Bs + r*128 + (((ksl*4 + l4) ^ (r&7))<<4));
      }
#pragma unroll
      for(int mf=0; mf<4; ++mf)
#pragma unroll
        for(int nf=0; nf<4; ++nf)
          acc[mf][nf] = __builtin_amdgcn_mfma_f32_16x16x32_f16(af[mf], bf[nf], acc[mf][nf], 0, 0, 0);
    }
  }
#pragma unroll
  for(int mf=0; mf<4; ++mf)
#pragma unroll
    for(int nf=0; nf<4; ++nf){
      int col = n0 + wc*64 + nf*16 + l15;
#pragma unroll
      for(int rg=0; rg<4; ++rg){
        int rowi = i0 + wr*64 + mf*16 + l4*4 + rg;
        C[(size_t)rowi*Nc + col] = (_Float16)acc[mf][nf][rg];
      }
    }
}

// ---------- CSR by dst ----------
__global__ void k_cnt(const int* __restrict__ dst, int* __restrict__ cnt){
  int e = blockIdx.x*blockDim.x + threadIdx.x;
  if(e < N_EDGES) atomicAdd(&cnt[dst[e]], 1);
}
__global__ void k_scan(const int* __restrict__ cnt, int* __restrict__ rowptr){
  __shared__ int part[1024];
  const int PER = 10;
  int tid = threadIdx.x;
  int base = tid*PER;
  int loc[PER];
  int s=0;
#pragma unroll
  for(int q=0;q<PER;q++){ int idx=base+q; int v=(idx<N_NODES)?cnt[idx]:0; loc[q]=v; s+=v; }
  part[tid]=s; __syncthreads();
  for(int off=1; off<1024; off<<=1){
    int v = (tid>=off) ? part[tid-off] : 0;
    __syncthreads();
    part[tid] += v;
    __syncthreads();
  }
  int run = (tid>0) ? part[tid-1] : 0;
#pragma unroll
  for(int q=0;q<PER;q++){ int idx=base+q; if(idx<N_NODES) rowptr[idx]=run; run+=loc[q]; }
  if(tid==1023) rowptr[N_NODES]=part[1023];
}
// fill CSR with pre-combined weights: scsr = src, wcsr = dinv[src]*ew
__global__ void k_fill2(const int* __restrict__ dst, const int* __restrict__ src,
                        const float* __restrict__ ew, const float* __restrict__ dinv,
                        const int* __restrict__ rowptr, int* __restrict__ fill,
                        int* __restrict__ scsr, float* __restrict__ wcsr){
  int e = blockIdx.x*blockDim.x + threadIdx.x;
  if(e >= N_EDGES) return;
  int d = dst[e];
  int pos = atomicAdd(&fill[d], 1);
  int idx = rowptr[d] + pos;
  int s = src[e];
  scsr[idx] = s;
  wcsr[idx] = dinv[s]*ew[e];
}

// ---------- GCN aggregation, LDS-staged CSR row + 4x unrolled gathers ----------
template<int F, typename OutT>
__global__ void k_agg2(const _Float16* __restrict__ hw, const float* __restrict__ bias,
                       const int* __restrict__ rowptr, const int* __restrict__ scsr,
                       const float* __restrict__ wcsr, const float* __restrict__ dinv,
                       OutT* __restrict__ out){
  const int v = blockIdx.x;
  const int tid = threadIdx.x;          // F/4 threads
  const int NT = F/4;
  __shared__ int   ss[256];
  __shared__ float sw[256];
  const half4* hp = (const half4*)hw;   // row stride F/4 half4s
  float dv = dinv[v];
  half4 hs = hp[(size_t)v*NT + tid];
  float a0 = dv*(float)hs[0], a1 = dv*(float)hs[1], a2 = dv*(float)hs[2], a3 = dv*(float)hs[3];
  int b = rowptr[v], e = rowptr[v+1];
  for(int base=b; base<e; base+=256){
    int m = min(256, e-base);
    __syncthreads();
    for(int t=tid; t<m; t+=NT){ ss[t]=scsr[base+t]; sw[t]=wcsr[base+t]; }
    __syncthreads();
    int t=0;
    for(; t+4<=m; t+=4){
      int s0=ss[t], s1=ss[t+1], s2=ss[t+2], s3=ss[t+3];
      float w0=sw[t], w1=sw[t+1], w2=sw[t+2], w3=sw[t+3];
      half4 h0 = hp[(size_t)s0*NT + tid];
      half4 h1 = hp[(size_t)s1*NT + tid];
      half4 h2 = hp[(size_t)s2*NT + tid];
      half4 h3 = hp[(size_t)s3*NT + tid];
      a0 += w0*(float)h0[0] + w1*(float)h1[0] + w2*(float)h2[0] + w3*(float)h3[0];
      a1 += w0*(float)h0[1] + w1*(float)h1[1] + w2*(float)h2[1] + w3*(float)h3[1];
      a2 += w0*(float)h0[2] + w1*(float)h1[2] + w2*(float)h2[2] + w3*(float)h3[2];
      a3 += w0*(float)h0[3] + w1*(float)h1[3] + w2*(float)h2[3] + w3*(float)h3[3];
    }
    for(; t<m; ++t){
      int s=ss[t]; float w=sw[t];
      half4 h = hp[(size_t)s*NT + tid];
      a0 += w*(float)h[0]; a1 += w*(float)h[1]; a2 += w*(float)h[2]; a3 += w*(float)h[3];
    }
  }
  int f0 = tid*4;
  float r0 = fmaxf(dv*a0 + bias[f0  ], 0.f);
  float r1 = fmaxf(dv*a1 + bias[f0+1], 0.f);
  float r2 = fmaxf(dv*a2 + bias[f0+2], 0.f);
  float r3 = fmaxf(dv*a3 + bias[f0+3], 0.f);
  if constexpr (sizeof(OutT)==2){
    half4 o; o[0]=(_Float16)r0; o[1]=(_Float16)r1; o[2]=(_Float16)r2; o[3]=(_Float16)r3;
    *(half4*)(out + (size_t)v*F + f0) = o;
  } else {
    float4 o = make_float4(r0,r1,r2,r3);
    *(float4*)(out + (size_t)v*F + f0) = o;
  }
}

extern "C" void kernel_launch(void* const* d_in, const int* in_sizes, int n_in,
                              void* d_out, int out_size, void* d_ws, size_t ws_size,
                              hipStream_t stream){
  const float* x   = (const float*)d_in[0];
  const float* pz1 = (const float*)d_in[1];
  const float* pz2 = (const float*)d_in[2];
  const float* W0  = (const float*)d_in[3];
  const float* b0  = (const float*)d_in[4];
  const float* W1  = (const float*)d_in[5];
  const float* b1  = (const float*)d_in[6];
  const int*   ei  = (const int*)d_in[7];
  const int* src = ei;
  const int* dst = ei + N_EDGES;
  float* out = (float*)d_out;

  char* ws = (char*)d_ws;
  size_t off = 0;
  auto alloc = [&](size_t bytes)->char*{
    char* p = ws + off;
    off += (bytes + 255) & ~(size_t)255;
    return p;
  };

  _Float16* z1h  = (_Float16*)alloc((size_t)NPAD*ZDIM*2);   // reused as hw1h after k_edge_w
  _Float16* z2h  = (_Float16*)alloc((size_t)NPAD*ZDIM*2);
  _Float16* xh   = (_Float16*)alloc((size_t)NPAD*512*2);
  _Float16* hw0h = (_Float16*)alloc((size_t)NPAD*512*2);
  _Float16* h1h  = (_Float16*)alloc((size_t)NPAD*512*2);
  _Float16* W0T  = (_Float16*)alloc((size_t)512*512*2);
  _Float16* W1T  = (_Float16*)alloc((size_t)256*512*2);
  float* ew      = (float*)alloc((size_t)N_EDGES*4);
  float* dsum    = (float*)alloc(NPAD*4);
  float* t1s     = (float*)alloc(NPAD*4);
  float* t2s     = (float*)alloc(NPAD*4);
  float* inv_nb  = (float*)alloc(NPAD*4);
  float* sii     = (float*)alloc(NPAD*4);
  float* degw    = (float*)alloc(NPAD*4);
  float* dinv    = (float*)alloc(NPAD*4);
  float* scal    = (float*)alloc(256);
  int* deg       = (int*)alloc(NPAD*4);
  int* cnt       = (int*)alloc(NPAD*4);
  int* rowptr    = (int*)alloc((NPAD+1)*4);
  int* fill      = (int*)alloc(NPAD*4);
  int* scsr      = (int*)alloc((size_t)N_EDGES*4);
  float* wcsr    = (float*)alloc((size_t)N_EDGES*4);
  unsigned* hkey = (unsigned*)alloc((size_t)HCAP*4);
  unsigned* hcnt = (unsigned*)alloc((size_t)HCAP*4);
  _Float16* hw1h = z1h;     // [NPAD,256] fp16, z1h dead after k_edge_w

  hipMemsetAsync(dsum, 0, NPAD*4, stream);
  hipMemsetAsync(t1s,  0, NPAD*4, stream);
  hipMemsetAsync(t2s,  0, NPAD*4, stream);
  hipMemsetAsync(deg,  0, NPAD*4, stream);
  hipMemsetAsync(cnt,  0, NPAD*4, stream);
  hipMemsetAsync(fill, 0, NPAD*4, stream);
  hipMemsetAsync(hkey, 0xFF, (size_t)HCAP*4, stream);
  hipMemsetAsync(hcnt, 0,    (size_t)HCAP*4, stream);

  const int EB = (N_EDGES+255)/256;

  // similarity pipeline
  k_l2norm_h<<<NPAD, 256, 0, stream>>>(pz1, z1h, N_NODES);
  k_l2norm_h<<<NPAD, 256, 0, stream>>>(pz2, z2h, N_NODES);
  k_deg_out<<<EB, 256, 0, stream>>>(src, deg);
  k_inv_nb<<<(NPAD+255)/256, 256, 0, stream>>>(deg, inv_nb);
  k_hash_insert<<<EB, 256, 0, stream>>>(src, dst, hkey, hcnt);
  k_diag_h<<<(N_NODES*64+255)/256, 256, 0, stream>>>(z1h, z2h, sii);
  k_stats_mfma<<<dim3(79, YS), 256, 0, stream>>>(z1h, z2h, inv_nb, dsum, t1s, t2s);
  k_finalize<<<1, 256, 0, stream>>>(dsum, t1s, t2s, inv_nb, sii, scal);
  k_edge_w<<<(N_EDGES*16)/256, 256, 0, stream>>>(src, dst, z1h, z2h, dsum, inv_nb, sii, scal, hkey, hcnt, ew);

  // GCN prep (overlappable small kernels)
  k_cast_pad<<<(int)(((size_t)NPAD*512/8 + 255)/256), 256, 0, stream>>>(x, xh, N_NODES, 512);
  k_transpose_h<<<dim3(16,16), dim3(32,8), 0, stream>>>(W0, W0T, 512, 512);
  k_transpose_h<<<dim3(8,16),  dim3(32,8), 0, stream>>>(W1, W1T, 512, 256);

  k_set1<<<(N_NODES+255)/256, 256, 0, stream>>>(degw, N_NODES);
  k_degw<<<EB, 256, 0, stream>>>(dst, ew, degw);
  k_dinv<<<(N_NODES+255)/256, 256, 0, stream>>>(degw, dinv);

  k_cnt<<<EB, 256, 0, stream>>>(dst, cnt);
  k_scan<<<1, 1024, 0, stream>>>(cnt, rowptr);
  k_fill2<<<EB, 256, 0, stream>>>(dst, src, ew, dinv, rowptr, fill, scsr, wcsr);

  // layer 1: hw0h = fp16(xh @ W0); h1h = fp16(relu(agg(hw0h) + b0))
  k_gemm_h<<<dim3(79, 4), 256, 0, stream>>>(xh, W0T, hw0h, 512, 512);
  k_agg2<512,_Float16><<<N_NODES, 128, 0, stream>>>(hw0h, b0, rowptr, scsr, wcsr, dinv, h1h);
  // layer 2: hw1h = fp16(h1h @ W1); out = relu(agg(hw1h) + b1)
  k_gemm_h<<<dim3(79, 2), 256, 0, stream>>>(h1h, W1T, hw1h, 512, 256);
  k_agg2<256,float><<<N_NODES, 64, 0, stream>>>(hw1h, b1, rowptr, scsr, wcsr, dinv, out);

  (void)in_sizes; (void)n_in; (void)out_size; (void)ws_size;
}

// Round 4
// 520.689 us; speedup vs baseline: 3.6573x; 1.1228x over previous
//
#include <hip/hip_runtime.h>
#include <math.h>

#define N_NODES 10000
#define N_EDGES 320000
#define ZDIM    256
#define NPAD    10112          // 79 * 128
#define PAD_J   112.0f         // padded cols contribute exp2(0)=1 to row sums
#define HCAP    (1u<<19)
#define HMASK   (HCAP-1u)
#define HEMPTY  0xFFFFFFFFu
#define TWO_LOG2E 2.8853900817779268f   // z1 pre-scale: exp(dot/0.5) = exp2(dot*2log2e)
#define LOG2E     1.4426950408889634f

typedef _Float16 half8 __attribute__((ext_vector_type(8)));
typedef _Float16 half4 __attribute__((ext_vector_type(4)));
typedef float f32x4 __attribute__((ext_vector_type(4)));

__device__ __forceinline__ float wave_red_sum64(float v){
#pragma unroll
  for(int off=1; off<64; off<<=1) v += __shfl_xor(v, off, 64);
  return v;
}

// ---------- row L2 normalize -> fp16, optional pre-scale (zero pad rows) ----------
__global__ void k_l2norm_h(const float* __restrict__ z, _Float16* __restrict__ zh, int rows, float mul){
  int r = blockIdx.x;
  int t = threadIdx.x;
  float v = (r < rows) ? z[(size_t)r*ZDIM + t] : 0.f;
  float s = wave_red_sum64(v*v);
  __shared__ float red[4];
  int lane = t & 63, wid = t >> 6;
  if(lane==0) red[wid]=s;
  __syncthreads();
  float tot = red[0]+red[1]+red[2]+red[3];
  float scale = mul/fmaxf(sqrtf(tot), 1e-12f);
  zh[(size_t)r*ZDIM + t] = (_Float16)(v*scale);
}

// ---------- out-degree (counting duplicates) ----------
__global__ void k_deg_out(const int* __restrict__ src, int* __restrict__ deg){
  int e = blockIdx.x*blockDim.x + threadIdx.x;
  if(e < N_EDGES) atomicAdd(&deg[src[e]], 1);
}
__global__ void k_inv_nb(const int* __restrict__ deg, float* __restrict__ inv_nb){
  int i = blockIdx.x*blockDim.x + threadIdx.x;
  if(i < NPAD) inv_nb[i] = (i < N_NODES) ? 1.f/sqrtf((float)deg[i] + 1.f) : 0.f;
}

// ---------- duplicate-edge multiplicity hash ----------
__global__ void k_hash_insert(const int* __restrict__ src, const int* __restrict__ dst,
                              unsigned* __restrict__ hkey, unsigned* __restrict__ hcnt){
  int e = blockIdx.x*blockDim.x + threadIdx.x;
  if(e >= N_EDGES) return;
  unsigned key = (unsigned)src[e]*10000u + (unsigned)dst[e];
  unsigned slot = (key * 2654435761u) & HMASK;
  while(true){
    unsigned old = atomicCAS(&hkey[slot], HEMPTY, key);
    if(old==HEMPTY || old==key){ atomicAdd(&hcnt[slot], 1u); break; }
    slot = (slot+1) & HMASK;
  }
}

// ---------- diagonal S_ii (scaled: z1h carries 2log2e) ----------
__global__ void k_diag_h(const _Float16* __restrict__ z1h, const _Float16* __restrict__ z2h,
                         float* __restrict__ sii){
  int gt = blockIdx.x*blockDim.x + threadIdx.x;
  int n = gt >> 6, lane = gt & 63;
  if(n >= N_NODES) return;
  half4 x = *(const half4*)(z1h + (size_t)n*ZDIM + lane*4);
  half4 y = *(const half4*)(z2h + (size_t)n*ZDIM + lane*4);
  float s = (float)x[0]*(float)y[0] + (float)x[1]*(float)y[1]
          + (float)x[2]*(float)y[2] + (float)x[3]*(float)y[3];
  s = wave_red_sum64(s);
  if(lane==0) sii[n] = s;
}

// ---------- MFMA fp16 streaming stats, m97-shape ----------
// grid (79,79): 128x128 tile, K=256 in 4 steps, global_load_lds staging,
// swizzle via pre-swizzled global source (involution: c ^= row&7 on 16B granules).
__launch_bounds__(256, 4)
__global__ void k_stats_mfma(const _Float16* __restrict__ z1h, const _Float16* __restrict__ z2h,
                             const float* __restrict__ inv_nb,
                             float* __restrict__ dsum, float* __restrict__ t1s, float* __restrict__ t2s){
  __shared__ _Float16 As[128*64];    // 16 KB per k-step
  __shared__ _Float16 Bs[128*64];    // 16 KB
  const int tid  = threadIdx.x;
  const int lane = tid & 63, w = tid >> 6;
  const int wr = w >> 1, wc = w & 1;
  const int l15 = lane & 15, l4 = lane >> 4;
  const int i0 = blockIdx.x * 128;
  const int n0 = blockIdx.y * 128;

  f32x4 acc[4][4];
#pragma unroll
  for(int a=0;a<4;a++)
#pragma unroll
    for(int b=0;b<4;b++) acc[a][b] = (f32x4){0.f,0.f,0.f,0.f};

  for(int kc=0; kc<ZDIM; kc+=64){
    __syncthreads();                       // prev k-step's ds_reads done
#pragma unroll
    for(int q=0;q<4;q++){
      int s = w*256 + q*64 + lane;         // linear 16B slot
      int row = s >> 3;
      int c   = (s & 7) ^ (row & 7);       // inverse swizzle on source
      __builtin_amdgcn_global_load_lds(
        (const __attribute__((address_space(1))) unsigned*)(z1h + (size_t)(i0+row)*ZDIM + kc + c*8),
        (__attribute__((address_space(3))) unsigned*)(As + (size_t)(w*256 + q*64)*8),
        16, 0, 0);
      __builtin_amdgcn_global_load_lds(
        (const __attribute__((address_space(1))) unsigned*)(z2h + (size_t)(n0+row)*ZDIM + kc + c*8),
        (__attribute__((address_space(3))) unsigned*)(Bs + (size_t)(w*256 + q*64)*8),
        16, 0, 0);
    }
    __syncthreads();                       // staging complete (vmcnt drained)
#pragma unroll
    for(int ksl=0; ksl<2; ++ksl){
      half8 af[4], bf[4];
#pragma unroll
      for(int mf=0; mf<4; ++mf){
        int r = wr*64 + mf*16 + l15;
        af[mf] = *(const half8*)((const char*)As + r*128 + (((ksl*4 + l4) ^ (r&7))<<4));
      }
#pragma unroll
      for(int nf=0; nf<4; ++nf){
        int r = wc*64 + nf*16 + l15;
        bf[nf] = *(const half8*)((const char*)Bs + r*128 + (((ksl*4 + l4) ^ (r&7))<<4));
      }
#pragma unroll
      for(int mf=0; mf<4; ++mf)
#pragma unroll
        for(int nf=0; nf<4; ++nf)
          acc[mf][nf] = __builtin_amdgcn_mfma_f32_16x16x32_f16(af[mf], bf[nf], acc[mf][nf], 0, 0, 0);
    }
  }

  // epilogue: e = exp2(acc) (z1 pre-scaled), per-row d/t1/t2
  float inbv[4];
#pragma unroll
  for(int nf=0;nf<4;nf++) inbv[nf] = inv_nb[n0 + wc*64 + nf*16 + l15];

  float dacc[4][4], t1a[4][4], t2a[4][4];
#pragma unroll
  for(int mf=0; mf<4; ++mf)
#pragma unroll
    for(int rg=0; rg<4; ++rg){ dacc[mf][rg]=0.f; t1a[mf][rg]=0.f; t2a[mf][rg]=0.f; }

#pragma unroll
  for(int mf=0; mf<4; ++mf)
#pragma unroll
    for(int nf=0; nf<4; ++nf){
      float inb = inbv[nf], inb2 = inb*inb;
#pragma unroll
      for(int rg=0; rg<4; ++rg){
        float e = exp2f(acc[mf][nf][rg]);
        dacc[mf][rg] += e;
        t1a[mf][rg] = fmaf(e, inb, t1a[mf][rg]);
        t2a[mf][rg] = fmaf(e*e, inb2, t2a[mf][rg]);
      }
    }

#pragma unroll
  for(int mf=0; mf<4; ++mf)
#pragma unroll
    for(int rg=0; rg<4; ++rg){
      float d = dacc[mf][rg], t1 = t1a[mf][rg], t2 = t2a[mf][rg];
#pragma unroll
      for(int off=1; off<16; off<<=1){
        d  += __shfl_xor(d,  off, 64);
        t1 += __shfl_xor(t1, off, 64);
        t2 += __shfl_xor(t2, off, 64);
      }
      if(l15==0){
        int i = i0 + wr*64 + mf*16 + l4*4 + rg;
        atomicAdd(&dsum[i], d);
        atomicAdd(&t1s[i], t1);
        atomicAdd(&t2s[i], t2);
      }
    }
}

// ---------- global mean/std of P and P5 (fp64 reduce) ----------
__global__ void k_finalize(const float* __restrict__ dsum, const float* __restrict__ t1s,
                           const float* __restrict__ t2s, const float* __restrict__ inv_nb,
                           const float* __restrict__ sii, float* __restrict__ scal){
  int tid = threadIdx.x;
  double A=0,B=0,S1=0,S2=0,Snb=0,Snb2=0;
  for(int i=tid;i<N_NODES;i+=256){
    float d   = dsum[i] - PAD_J;
    float inb = inv_nb[i];
    float t1  = t1s[i], t2 = t2s[i];
    A += (double)(t1*inb/d);
    B += (double)((t2*inb*inb)/(d*d));
    float eii = exp2f(sii[i]);
    float ci  = fabsf(eii/d - 1.f)*inb;
    S1 += (double)ci; S2 += (double)ci*(double)ci;
    Snb += (double)inb; Snb2 += (double)inb*(double)inb;
  }
  __shared__ double red[256];
  double vals[6]={A,B,S1,S2,Snb,Snb2};
  double out[6];
  for(int v=0;v<6;v++){
    red[tid]=vals[v]; __syncthreads();
    for(int off=128;off;off>>=1){ if(tid<off) red[tid]+=red[tid+off]; __syncthreads(); }
    out[v]=red[0]; __syncthreads();
  }
  if(tid==0){
    double M = (double)N_NODES*(double)N_NODES;
    double mean  = out[0]/M;
    double var   = (out[1] - out[0]*out[0]/M)/(M-1.0);
    double sp5   = out[2]*out[4];
    double mean5 = sp5/M;
    double var5  = (out[3]*out[5] - sp5*sp5/M)/(M-1.0);
    scal[0]=(float)mean;  scal[1]=(float)(1.0/sqrt(var));
    scal[2]=(float)mean5; scal[3]=(float)(1.0/sqrt(var5));
  }
}

// ---------- per-edge weight: 16 lanes per edge ----------
__global__ void k_edge_w(const int* __restrict__ src, const int* __restrict__ dst,
                         const _Float16* __restrict__ z1h, const _Float16* __restrict__ z2h,
                         const float* __restrict__ dsum, const float* __restrict__ inv_nb,
                         const float* __restrict__ sii, const float* __restrict__ scal,
                         const unsigned* __restrict__ hkey, const unsigned* __restrict__ hcnt,
                         float* __restrict__ ew){
  int gt = blockIdx.x*blockDim.x + threadIdx.x;
  int e = gt >> 4, l = gt & 15;
  if(e >= N_EDGES) return;
  int s = src[e], d = dst[e];
  half8 x0 = *(const half8*)(z1h + (size_t)s*ZDIM + l*16);
  half8 x1 = *(const half8*)(z1h + (size_t)s*ZDIM + l*16 + 8);
  half8 y0 = *(const half8*)(z2h + (size_t)d*ZDIM + l*16);
  half8 y1 = *(const half8*)(z2h + (size_t)d*ZDIM + l*16 + 8);
  float dot = 0.f;
#pragma unroll
  for(int q=0;q<8;q++) dot = fmaf((float)x0[q], (float)y0[q], dot);
#pragma unroll
  for(int q=0;q<8;q++) dot = fmaf((float)x1[q], (float)y1[q], dot);
#pragma unroll
  for(int off=1; off<16; off<<=1) dot += __shfl_xor(dot, off, 64);
  if(l==0){
    float ds = dsum[s] - PAD_J;
    float P  = exp2f(dot)/ds * inv_nb[s]*inv_nb[d];
    float z  = (P - scal[0])*scal[1];
    float p12 = 1.f/(1.f + exp2f(-z*LOG2E));
    float eii = exp2f(sii[s]);
    float c5  = fabsf(eii/ds - 1.f)*inv_nb[s]*inv_nb[d];
    float z5  = (c5 - scal[2])*scal[3];
    float p5  = 1.f/(1.f + exp2f(-z5*LOG2E));
    unsigned key  = (unsigned)s*10000u + (unsigned)d;
    unsigned slot = (key*2654435761u) & HMASK;
    while(hkey[slot] != key) slot = (slot+1) & HMASK;
    ew[e] = 0.5f*(p5 + p12) * (float)hcnt[slot];
  }
}

// ---------- GCN degree / dinv ----------
__global__ void k_set1(float* __restrict__ p, int n){
  int i = blockIdx.x*blockDim.x + threadIdx.x;
  if(i<n) p[i]=1.f;
}
__global__ void k_degw(const int* __restrict__ dst, const float* __restrict__ ew,
                       float* __restrict__ degw){
  int e = blockIdx.x*blockDim.x + threadIdx.x;
  if(e < N_EDGES) atomicAdd(&degw[dst[e]], ew[e]);
}
__global__ void k_dinv(const float* __restrict__ degw, float* __restrict__ dinv){
  int i = blockIdx.x*blockDim.x + threadIdx.x;
  if(i < N_NODES) dinv[i] = 1.f/sqrtf(degw[i]);
}

// ---------- cast fp32 -> fp16 with zero row padding ----------
__global__ void k_cast_pad(const float* __restrict__ A, _Float16* __restrict__ Ah, int M, int K){
  size_t t = (size_t)blockIdx.x*256 + threadIdx.x;
  size_t total = (size_t)NPAD*K/8;
  if(t >= total) return;
  size_t base = t*8;
  int row = (int)(base / (size_t)K);
  half8 o;
  if(row < M){
    float4 v0 = *(const float4*)(A + base);
    float4 v1 = *(const float4*)(A + base + 4);
    o[0]=(_Float16)v0.x; o[1]=(_Float16)v0.y; o[2]=(_Float16)v0.z; o[3]=(_Float16)v0.w;
    o[4]=(_Float16)v1.x; o[5]=(_Float16)v1.y; o[6]=(_Float16)v1.z; o[7]=(_Float16)v1.w;
  } else {
#pragma unroll
    for(int q=0;q<8;q++) o[q]=(_Float16)0.f;
  }
  *(half8*)(Ah + base) = o;
}

// ---------- transpose + cast: WT[n][k] = (fp16)W[k][n] ----------
__global__ void k_transpose_h(const float* __restrict__ W, _Float16* __restrict__ WT, int K, int N){
  __shared__ float t[32][33];
  int bx = blockIdx.x*32, by = blockIdx.y*32;
  int tx = threadIdx.x, ty = threadIdx.y;       // 32 x 8
  for(int r=ty; r<32; r+=8) t[r][tx] = W[(size_t)(by+r)*N + bx+tx];
  __syncthreads();
  for(int r=ty; r<32; r+=8) WT[(size_t)(bx+r)*K + by+tx] = (_Float16)t[tx][r];
}

// ---------- MFMA fp16 GEMM: C[NPAD,Nc](fp16) = Ah[NPAD,K] @ BT[Nc,K]^T ----------
__launch_bounds__(256, 2)
__global__ void k_gemm_h(const _Float16* __restrict__ Ah, const _Float16* __restrict__ BT,
                         _Float16* __restrict__ C, int K, int Nc){
  __shared__ _Float16 As[128*64];
  __shared__ _Float16 Bs[128*64];
  const int tid  = threadIdx.x;
  const int lane = tid & 63, w = tid >> 6;
  const int wr = w >> 1, wc = w & 1;
  const int l15 = lane & 15, l4 = lane >> 4;
  const int i0 = blockIdx.x * 128;
  const int n0 = blockIdx.y * 128;

  f32x4 acc[4][4];
#pragma unroll
  for(int a=0;a<4;a++)
#pragma unroll
    for(int b=0;b<4;b++) acc[a][b] = (f32x4){0.f,0.f,0.f,0.f};

  uint4 areg[4], brg[4];
#pragma unroll
  for(int q=0;q<4;q++){
    int g = tid + q*256;
    areg[q] = *(const uint4*)(Ah + (size_t)(i0 + (g>>3))*K + (g&7)*8);
    brg[q]  = *(const uint4*)(BT + (size_t)(n0 + (g>>3))*K + (g&7)*8);
  }

  for(int kc=0; kc<K; kc+=64){
    __syncthreads();
#pragma unroll
    for(int q=0;q<4;q++){
      int g = tid + q*256;
      int row = g>>3, c = g&7;
      *(uint4*)((char*)As + row*128 + ((c ^ (row&7))<<4)) = areg[q];
      *(uint4*)((char*)Bs + row*128 + ((c ^ (row&7))<<4)) = brg[q];
    }
    if(kc + 64 < K){
#pragma unroll
      for(int q=0;q<4;q++){
        int g = tid + q*256;
        areg[q] = *(const uint4*)(Ah + (size_t)(i0 + (g>>3))*K + kc + 64 + (g&7)*8);
        brg[q]  = *(const uint4*)(BT + (size_t)(n0 + (g>>3))*K + kc + 64 + (g&7)*8);
      }
    }
    __syncthreads();
#pragma unroll
    for(int ksl=0; ksl<2; ++ksl){
      half8 af[4], bf[4];
#pragma unroll
      for(int mf=0; mf<4; ++mf){
        int r = wr*64 + mf*16 + l15;
        af[mf] = *(const half8*)((const char*)As + r*128 + (((ksl*4 + l4) ^ (r&7))<<4));
      }
#pragma unroll
      for(int nf=0; nf<4; ++nf){
        int r = wc*64 + nf*16 + l15;
        bf[nf] = *(const half8*)((const char*)Bs + r*128 + (((ksl*4 + l4) ^ (r&7))<<4));
      }
#pragma unroll
      for(int mf=0; mf<4; ++mf)
#pragma unroll
        for(int nf=0; nf<4; ++nf)
          acc[mf][nf] = __builtin_amdgcn_mfma_f32_16x16x32_f16(af[mf], bf[nf], acc[mf][nf], 0, 0, 0);
    }
  }
#pragma unroll
  for(int mf=0; mf<4; ++mf)
#pragma unroll
    for(int nf=0; nf<4; ++nf){
      int col = n0 + wc*64 + nf*16 + l15;
#pragma unroll
      for(int rg=0; rg<4; ++rg){
        int rowi = i0 + wr*64 + mf*16 + l4*4 + rg;
        C[(size_t)rowi*Nc + col] = (_Float16)acc[mf][nf][rg];
      }
    }
}

// ---------- CSR by dst ----------
__global__ void k_cnt(const int* __restrict__ dst, int* __restrict__ cnt){
  int e = blockIdx.x*blockDim.x + threadIdx.x;
  if(e < N_EDGES) atomicAdd(&cnt[dst[e]], 1);
}
__global__ void k_scan(const int* __restrict__ cnt, int* __restrict__ rowptr){
  __shared__ int part[1024];
  const int PER = 10;
  int tid = threadIdx.x;
  int base = tid*PER;
  int loc[PER];
  int s=0;
#pragma unroll
  for(int q=0;q<PER;q++){ int idx=base+q; int v=(idx<N_NODES)?cnt[idx]:0; loc[q]=v; s+=v; }
  part[tid]=s; __syncthreads();
  for(int off=1; off<1024; off<<=1){
    int v = (tid>=off) ? part[tid-off] : 0;
    __syncthreads();
    part[tid] += v;
    __syncthreads();
  }
  int run = (tid>0) ? part[tid-1] : 0;
#pragma unroll
  for(int q=0;q<PER;q++){ int idx=base+q; if(idx<N_NODES) rowptr[idx]=run; run+=loc[q]; }
  if(tid==1023) rowptr[N_NODES]=part[1023];
}
__global__ void k_fill2(const int* __restrict__ dst, const int* __restrict__ src,
                        const float* __restrict__ ew, const float* __restrict__ dinv,
                        const int* __restrict__ rowptr, int* __restrict__ fill,
                        int* __restrict__ scsr, float* __restrict__ wcsr){
  int e = blockIdx.x*blockDim.x + threadIdx.x;
  if(e >= N_EDGES) return;
  int d = dst[e];
  int pos = atomicAdd(&fill[d], 1);
  int idx = rowptr[d] + pos;
  int s = src[e];
  scsr[idx] = s;
  wcsr[idx] = dinv[s]*ew[e];
}

// ---------- GCN aggregation, LDS-staged CSR row + 4x unrolled gathers ----------
template<int F, typename OutT>
__global__ void k_agg2(const _Float16* __restrict__ hw, const float* __restrict__ bias,
                       const int* __restrict__ rowptr, const int* __restrict__ scsr,
                       const float* __restrict__ wcsr, const float* __restrict__ dinv,
                       OutT* __restrict__ out){
  const int v = blockIdx.x;
  const int tid = threadIdx.x;          // F/4 threads
  const int NT = F/4;
  __shared__ int   ss[256];
  __shared__ float sw[256];
  const half4* hp = (const half4*)hw;
  float dv = dinv[v];
  half4 hs = hp[(size_t)v*NT + tid];
  float a0 = dv*(float)hs[0], a1 = dv*(float)hs[1], a2 = dv*(float)hs[2], a3 = dv*(float)hs[3];
  int b = rowptr[v], e = rowptr[v+1];
  for(int base=b; base<e; base+=256){
    int m = min(256, e-base);
    __syncthreads();
    for(int t=tid; t<m; t+=NT){ ss[t]=scsr[base+t]; sw[t]=wcsr[base+t]; }
    __syncthreads();
    int t=0;
    for(; t+4<=m; t+=4){
      int s0=ss[t], s1=ss[t+1], s2=ss[t+2], s3=ss[t+3];
      float w0=sw[t], w1=sw[t+1], w2=sw[t+2], w3=sw[t+3];
      half4 h0 = hp[(size_t)s0*NT + tid];
      half4 h1 = hp[(size_t)s1*NT + tid];
      half4 h2 = hp[(size_t)s2*NT + tid];
      half4 h3 = hp[(size_t)s3*NT + tid];
      a0 += w0*(float)h0[0] + w1*(float)h1[0] + w2*(float)h2[0] + w3*(float)h3[0];
      a1 += w0*(float)h0[1] + w1*(float)h1[1] + w2*(float)h2[1] + w3*(float)h3[1];
      a2 += w0*(float)h0[2] + w1*(float)h1[2] + w2*(float)h2[2] + w3*(float)h3[2];
      a3 += w0*(float)h0[3] + w1*(float)h1[3] + w2*(float)h2[3] + w3*(float)h3[3];
    }
    for(; t<m; ++t){
      int s=ss[t]; float w=sw[t];
      half4 h = hp[(size_t)s*NT + tid];
      a0 += w*(float)h[0]; a1 += w*(float)h[1]; a2 += w*(float)h[2]; a3 += w*(float)h[3];
    }
  }
  int f0 = tid*4;
  float r0 = fmaxf(dv*a0 + bias[f0  ], 0.f);
  float r1 = fmaxf(dv*a1 + bias[f0+1], 0.f);
  float r2 = fmaxf(dv*a2 + bias[f0+2], 0.f);
  float r3 = fmaxf(dv*a3 + bias[f0+3], 0.f);
  if constexpr (sizeof(OutT)==2){
    half4 o; o[0]=(_Float16)r0; o[1]=(_Float16)r1; o[2]=(_Float16)r2; o[3]=(_Float16)r3;
    *(half4*)(out + (size_t)v*F + f0) = o;
  } else {
    float4 o = make_float4(r0,r1,r2,r3);
    *(float4*)(out + (size_t)v*F + f0) = o;
  }
}

extern "C" void kernel_launch(void* const* d_in, const int* in_sizes, int n_in,
                              void* d_out, int out_size, void* d_ws, size_t ws_size,
                              hipStream_t stream){
  const float* x   = (const float*)d_in[0];
  const float* pz1 = (const float*)d_in[1];
  const float* pz2 = (const float*)d_in[2];
  const float* W0  = (const float*)d_in[3];
  const float* b0  = (const float*)d_in[4];
  const float* W1  = (const float*)d_in[5];
  const float* b1  = (const float*)d_in[6];
  const int*   ei  = (const int*)d_in[7];
  const int* src = ei;
  const int* dst = ei + N_EDGES;
  float* out = (float*)d_out;

  char* ws = (char*)d_ws;
  size_t off = 0;
  auto alloc = [&](size_t bytes)->char*{
    char* p = ws + off;
    off += (bytes + 255) & ~(size_t)255;
    return p;
  };

  _Float16* z1h  = (_Float16*)alloc((size_t)NPAD*ZDIM*2);   // reused as hw1h after k_edge_w
  _Float16* z2h  = (_Float16*)alloc((size_t)NPAD*ZDIM*2);
  _Float16* xh   = (_Float16*)alloc((size_t)NPAD*512*2);
  _Float16* hw0h = (_Float16*)alloc((size_t)NPAD*512*2);
  _Float16* h1h  = (_Float16*)alloc((size_t)NPAD*512*2);
  _Float16* W0T  = (_Float16*)alloc((size_t)512*512*2);
  _Float16* W1T  = (_Float16*)alloc((size_t)256*512*2);
  float* ew      = (float*)alloc((size_t)N_EDGES*4);
  float* dsum    = (float*)alloc(NPAD*4);
  float* t1s     = (float*)alloc(NPAD*4);
  float* t2s     = (float*)alloc(NPAD*4);
  float* inv_nb  = (float*)alloc(NPAD*4);
  float* sii     = (float*)alloc(NPAD*4);
  float* degw    = (float*)alloc(NPAD*4);
  float* dinv    = (float*)alloc(NPAD*4);
  float* scal    = (float*)alloc(256);
  int* deg       = (int*)alloc(NPAD*4);
  int* cnt       = (int*)alloc(NPAD*4);
  int* rowptr    = (int*)alloc((NPAD+1)*4);
  int* fill      = (int*)alloc(NPAD*4);
  int* scsr      = (int*)alloc((size_t)N_EDGES*4);
  float* wcsr    = (float*)alloc((size_t)N_EDGES*4);
  unsigned* hkey = (unsigned*)alloc((size_t)HCAP*4);
  unsigned* hcnt = (unsigned*)alloc((size_t)HCAP*4);
  _Float16* hw1h = z1h;     // [NPAD,256] fp16, z1h dead after k_edge_w

  hipMemsetAsync(dsum, 0, NPAD*4, stream);
  hipMemsetAsync(t1s,  0, NPAD*4, stream);
  hipMemsetAsync(t2s,  0, NPAD*4, stream);
  hipMemsetAsync(deg,  0, NPAD*4, stream);
  hipMemsetAsync(cnt,  0, NPAD*4, stream);
  hipMemsetAsync(fill, 0, NPAD*4, stream);
  hipMemsetAsync(hkey, 0xFF, (size_t)HCAP*4, stream);
  hipMemsetAsync(hcnt, 0,    (size_t)HCAP*4, stream);

  const int EB = (N_EDGES+255)/256;

  // similarity pipeline (z1 pre-scaled by 2*log2e)
  k_l2norm_h<<<NPAD, 256, 0, stream>>>(pz1, z1h, N_NODES, TWO_LOG2E);
  k_l2norm_h<<<NPAD, 256, 0, stream>>>(pz2, z2h, N_NODES, 1.0f);
  k_deg_out<<<EB, 256, 0, stream>>>(src, deg);
  k_inv_nb<<<(NPAD+255)/256, 256, 0, stream>>>(deg, inv_nb);
  k_hash_insert<<<EB, 256, 0, stream>>>(src, dst, hkey, hcnt);
  k_diag_h<<<(N_NODES*64+255)/256, 256, 0, stream>>>(z1h, z2h, sii);
  k_stats_mfma<<<dim3(79, 79), 256, 0, stream>>>(z1h, z2h, inv_nb, dsum, t1s, t2s);
  k_finalize<<<1, 256, 0, stream>>>(dsum, t1s, t2s, inv_nb, sii, scal);
  k_edge_w<<<(N_EDGES*16)/256, 256, 0, stream>>>(src, dst, z1h, z2h, dsum, inv_nb, sii, scal, hkey, hcnt, ew);

  // GCN prep
  k_cast_pad<<<(int)(((size_t)NPAD*512/8 + 255)/256), 256, 0, stream>>>(x, xh, N_NODES, 512);
  k_transpose_h<<<dim3(16,16), dim3(32,8), 0, stream>>>(W0, W0T, 512, 512);
  k_transpose_h<<<dim3(8,16),  dim3(32,8), 0, stream>>>(W1, W1T, 512, 256);

  k_set1<<<(N_NODES+255)/256, 256, 0, stream>>>(degw, N_NODES);
  k_degw<<<EB, 256, 0, stream>>>(dst, ew, degw);
  k_dinv<<<(N_NODES+255)/256, 256, 0, stream>>>(degw, dinv);

  k_cnt<<<EB, 256, 0, stream>>>(dst, cnt);
  k_scan<<<1, 1024, 0, stream>>>(cnt, rowptr);
  k_fill2<<<EB, 256, 0, stream>>>(dst, src, ew, dinv, rowptr, fill, scsr, wcsr);

  // layer 1: hw0h = fp16(xh @ W0); h1h = fp16(relu(agg(hw0h) + b0))
  k_gemm_h<<<dim3(79, 4), 256, 0, stream>>>(xh, W0T, hw0h, 512, 512);
  k_agg2<512,_Float16><<<N_NODES, 128, 0, stream>>>(hw0h, b0, rowptr, scsr, wcsr, dinv, h1h);
  // layer 2: hw1h = fp16(h1h @ W1); out = relu(agg(hw1h) + b1)
  k_gemm_h<<<dim3(79, 2), 256, 0, stream>>>(h1h, W1T, hw1h, 512, 256);
  k_agg2<256,float><<<N_NODES, 64, 0, stream>>>(hw1h, b1, rowptr, scsr, wcsr, dinv, out);

  (void)in_sizes; (void)n_in; (void)out_size; (void)ws_size;
}

// Round 5
// 501.851 us; speedup vs baseline: 3.7946x; 1.0375x over previous
//
#include <hip/hip_runtime.h>
#include <math.h>

#define N_NODES 10000
#define N_EDGES 320000
#define ZDIM    256
#define NPAD    10112          // 79 * 128 = 158 * 64
#define PAD_J   112.0f         // padded cols contribute exp2(0)=1 to row sums
#define HCAP    (1u<<19)
#define HMASK   (HCAP-1u)
#define HEMPTY  0xFFFFFFFFu
#define TWO_LOG2E 2.8853900817779268f   // z1 pre-scale: exp(dot/0.5) = exp2(dot*2log2e)
#define LOG2E     1.4426950408889634f
#define NJB 79
#define PSTRIDE ((size_t)NJB*NPAD)

typedef _Float16 half8 __attribute__((ext_vector_type(8)));
typedef _Float16 half4 __attribute__((ext_vector_type(4)));
typedef float f32x4 __attribute__((ext_vector_type(4)));

__device__ __forceinline__ float wave_red_sum64(float v){
#pragma unroll
  for(int off=1; off<64; off<<=1) v += __shfl_xor(v, off, 64);
  return v;
}

// ---------- row L2 normalize (both arrays, one launch) -> fp16, z1 pre-scaled ----------
__global__ void k_l2norm2(const float* __restrict__ z1, const float* __restrict__ z2,
                          _Float16* __restrict__ o1, _Float16* __restrict__ o2, int rows){
  int r = blockIdx.x;
  int which = blockIdx.y;
  const float* z = which ? z2 : z1;
  _Float16* o = which ? o2 : o1;
  float mul = which ? 1.0f : TWO_LOG2E;
  int t = threadIdx.x;
  float v = (r < rows) ? z[(size_t)r*ZDIM + t] : 0.f;
  float s = wave_red_sum64(v*v);
  __shared__ float red[4];
  int lane = t & 63, wid = t >> 6;
  if(lane==0) red[wid]=s;
  __syncthreads();
  float tot = red[0]+red[1]+red[2]+red[3];
  float scale = mul/fmaxf(sqrtf(tot), 1e-12f);
  o[(size_t)r*ZDIM + t] = (_Float16)(v*scale);
}

// ---------- fused edge pass: src-degree, dst-degree, duplicate hash ----------
__global__ void k_edge_pre(const int* __restrict__ src, const int* __restrict__ dst,
                           int* __restrict__ deg, int* __restrict__ cnt,
                           unsigned* __restrict__ hkey, unsigned* __restrict__ hcnt){
  int e = blockIdx.x*blockDim.x + threadIdx.x;
  if(e >= N_EDGES) return;
  int s = src[e], d = dst[e];
  atomicAdd(&deg[s], 1);
  atomicAdd(&cnt[d], 1);
  unsigned key = (unsigned)s*10000u + (unsigned)d;
  unsigned slot = (key * 2654435761u) & HMASK;
  while(true){
    unsigned old = atomicCAS(&hkey[slot], HEMPTY, key);
    if(old==HEMPTY || old==key){ atomicAdd(&hcnt[slot], 1u); break; }
    slot = (slot+1) & HMASK;
  }
}
__global__ void k_inv_nb(const int* __restrict__ deg, float* __restrict__ inv_nb){
  int i = blockIdx.x*blockDim.x + threadIdx.x;
  if(i < NPAD) inv_nb[i] = (i < N_NODES) ? 1.f/sqrtf((float)deg[i] + 1.f) : 0.f;
}

// ---------- diagonal S_ii (scaled: z1h carries 2log2e) ----------
__global__ void k_diag_h(const _Float16* __restrict__ z1h, const _Float16* __restrict__ z2h,
                         float* __restrict__ sii){
  int gt = blockIdx.x*blockDim.x + threadIdx.x;
  int n = gt >> 6, lane = gt & 63;
  if(n >= N_NODES) return;
  half4 x = *(const half4*)(z1h + (size_t)n*ZDIM + lane*4);
  half4 y = *(const half4*)(z2h + (size_t)n*ZDIM + lane*4);
  float s = (float)x[0]*(float)y[0] + (float)x[1]*(float)y[1]
          + (float)x[2]*(float)y[2] + (float)x[3]*(float)y[3];
  s = wave_red_sum64(s);
  if(lane==0) sii[n] = s;
}

// ---------- MFMA fp16 streaming stats, XCD-chunked grid, partial stores (no atomics) ----------
// grid: 6320 linear blocks (79x80 padded). xcd = bid&7 owns j-columns [xcd*10, xcd*10+10);
// within chunk i varies slowest -> 10 j-panels stay L2-resident per XCD.
__launch_bounds__(256, 4)
__global__ void k_stats_mfma(const _Float16* __restrict__ z1h, const _Float16* __restrict__ z2h,
                             const float* __restrict__ inv_nb, float* __restrict__ parts){
  __shared__ _Float16 As[128*64];    // 16 KB per k-step
  __shared__ _Float16 Bs[128*64];    // 16 KB
  __shared__ float sred[2][3][128];  // 3 KB wc-combine
  const int bid = blockIdx.x;
  const int xcd = bid & 7, c = bid >> 3;
  const int ib = c / 10, jj = c - ib*10;
  const int jb = xcd*10 + jj;
  if(jb >= NJB) return;
  const int tid  = threadIdx.x;
  const int lane = tid & 63, w = tid >> 6;
  const int wr = w >> 1, wc = w & 1;
  const int l15 = lane & 15, l4 = lane >> 4;
  const int i0 = ib * 128;
  const int n0 = jb * 128;

  f32x4 acc[4][4];
#pragma unroll
  for(int a=0;a<4;a++)
#pragma unroll
    for(int b=0;b<4;b++) acc[a][b] = (f32x4){0.f,0.f,0.f,0.f};

  for(int kc=0; kc<ZDIM; kc+=64){
    __syncthreads();                       // prev k-step's ds_reads done
#pragma unroll
    for(int q=0;q<4;q++){
      int s = w*256 + q*64 + lane;         // linear 16B slot
      int row = s >> 3;
      int cg  = (s & 7) ^ (row & 7);       // inverse swizzle on source
      __builtin_amdgcn_global_load_lds(
        (const __attribute__((address_space(1))) unsigned*)(z1h + (size_t)(i0+row)*ZDIM + kc + cg*8),
        (__attribute__((address_space(3))) unsigned*)(As + (size_t)(w*256 + q*64)*8),
        16, 0, 0);
      __builtin_amdgcn_global_load_lds(
        (const __attribute__((address_space(1))) unsigned*)(z2h + (size_t)(n0+row)*ZDIM + kc + cg*8),
        (__attribute__((address_space(3))) unsigned*)(Bs + (size_t)(w*256 + q*64)*8),
        16, 0, 0);
    }
    __syncthreads();                       // staging complete
#pragma unroll
    for(int ksl=0; ksl<2; ++ksl){
      half8 af[4], bf[4];
#pragma unroll
      for(int mf=0; mf<4; ++mf){
        int r = wr*64 + mf*16 + l15;
        af[mf] = *(const half8*)((const char*)As + r*128 + (((ksl*4 + l4) ^ (r&7))<<4));
      }
#pragma unroll
      for(int nf=0; nf<4; ++nf){
        int r = wc*64 + nf*16 + l15;
        bf[nf] = *(const half8*)((const char*)Bs + r*128 + (((ksl*4 + l4) ^ (r&7))<<4));
      }
#pragma unroll
      for(int mf=0; mf<4; ++mf)
#pragma unroll
        for(int nf=0; nf<4; ++nf)
          acc[mf][nf] = __builtin_amdgcn_mfma_f32_16x16x32_f16(af[mf], bf[nf], acc[mf][nf], 0, 0, 0);
    }
  }

  // epilogue: e = exp2(acc), per-row d/t1/t2
  float inbv[4];
#pragma unroll
  for(int nf=0;nf<4;nf++) inbv[nf] = inv_nb[n0 + wc*64 + nf*16 + l15];

  float dacc[4][4], t1a[4][4], t2a[4][4];
#pragma unroll
  for(int mf=0; mf<4; ++mf)
#pragma unroll
    for(int rg=0; rg<4; ++rg){ dacc[mf][rg]=0.f; t1a[mf][rg]=0.f; t2a[mf][rg]=0.f; }

#pragma unroll
  for(int mf=0; mf<4; ++mf)
#pragma unroll
    for(int nf=0; nf<4; ++nf){
      float inb = inbv[nf], inb2 = inb*inb;
#pragma unroll
      for(int rg=0; rg<4; ++rg){
        float e = exp2f(acc[mf][nf][rg]);
        dacc[mf][rg] += e;
        t1a[mf][rg] = fmaf(e, inb, t1a[mf][rg]);
        t2a[mf][rg] = fmaf(e*e, inb2, t2a[mf][rg]);
      }
    }

#pragma unroll
  for(int mf=0; mf<4; ++mf)
#pragma unroll
    for(int rg=0; rg<4; ++rg){
      float d = dacc[mf][rg], t1 = t1a[mf][rg], t2 = t2a[mf][rg];
#pragma unroll
      for(int off=1; off<16; off<<=1){
        d  += __shfl_xor(d,  off, 64);
        t1 += __shfl_xor(t1, off, 64);
        t2 += __shfl_xor(t2, off, 64);
      }
      if(l15==0){
        int il = wr*64 + mf*16 + l4*4 + rg;
        sred[wc][0][il] = d;
        sred[wc][1][il] = t1;
        sred[wc][2][il] = t2;
      }
    }
  __syncthreads();
  if(tid < 128){
#pragma unroll
    for(int s=0;s<3;s++){
      float v = sred[0][s][tid] + sred[1][s][tid];
      parts[(size_t)s*PSTRIDE + (size_t)jb*NPAD + i0 + tid] = v;
    }
  }
}

// ---------- reduce partials over jb ----------
__global__ void k_redparts(const float* __restrict__ parts, float* __restrict__ dsum,
                           float* __restrict__ t1s, float* __restrict__ t2s){
  int i = blockIdx.x*256 + threadIdx.x;
  if(i >= NPAD) return;
  float a=0.f, b=0.f, c=0.f;
  for(int j=0;j<NJB;j++){
    a += parts[(size_t)j*NPAD + i];
    b += parts[PSTRIDE + (size_t)j*NPAD + i];
    c += parts[2*PSTRIDE + (size_t)j*NPAD + i];
  }
  dsum[i]=a; t1s[i]=b; t2s[i]=c;
}

// ---------- global mean/std of P and P5 (fp64 reduce) ----------
__global__ void k_finalize(const float* __restrict__ dsum, const float* __restrict__ t1s,
                           const float* __restrict__ t2s, const float* __restrict__ inv_nb,
                           const float* __restrict__ sii, float* __restrict__ scal){
  int tid = threadIdx.x;
  double A=0,B=0,S1=0,S2=0,Snb=0,Snb2=0;
  for(int i=tid;i<N_NODES;i+=256){
    float d   = dsum[i] - PAD_J;
    float inb = inv_nb[i];
    float t1  = t1s[i], t2 = t2s[i];
    A += (double)(t1*inb/d);
    B += (double)((t2*inb*inb)/(d*d));
    float eii = exp2f(sii[i]);
    float ci  = fabsf(eii/d - 1.f)*inb;
    S1 += (double)ci; S2 += (double)ci*(double)ci;
    Snb += (double)inb; Snb2 += (double)inb*(double)inb;
  }
  __shared__ double red[256];
  double vals[6]={A,B,S1,S2,Snb,Snb2};
  double out[6];
  for(int v=0;v<6;v++){
    red[tid]=vals[v]; __syncthreads();
    for(int off=128;off;off>>=1){ if(tid<off) red[tid]+=red[tid+off]; __syncthreads(); }
    out[v]=red[0]; __syncthreads();
  }
  if(tid==0){
    double M = (double)N_NODES*(double)N_NODES;
    double mean  = out[0]/M;
    double var   = (out[1] - out[0]*out[0]/M)/(M-1.0);
    double sp5   = out[2]*out[4];
    double mean5 = sp5/M;
    double var5  = (out[3]*out[5] - sp5*sp5/M)/(M-1.0);
    scal[0]=(float)mean;  scal[1]=(float)(1.0/sqrt(var));
    scal[2]=(float)mean5; scal[3]=(float)(1.0/sqrt(var5));
  }
}

// ---------- per-edge weight: 16 lanes per edge ----------
__global__ void k_edge_w(const int* __restrict__ src, const int* __restrict__ dst,
                         const _Float16* __restrict__ z1h, const _Float16* __restrict__ z2h,
                         const float* __restrict__ dsum, const float* __restrict__ inv_nb,
                         const float* __restrict__ sii, const float* __restrict__ scal,
                         const unsigned* __restrict__ hkey, const unsigned* __restrict__ hcnt,
                         float* __restrict__ ew){
  int gt = blockIdx.x*blockDim.x + threadIdx.x;
  int e = gt >> 4, l = gt & 15;
  if(e >= N_EDGES) return;
  int s = src[e], d = dst[e];
  half8 x0 = *(const half8*)(z1h + (size_t)s*ZDIM + l*16);
  half8 x1 = *(const half8*)(z1h + (size_t)s*ZDIM + l*16 + 8);
  half8 y0 = *(const half8*)(z2h + (size_t)d*ZDIM + l*16);
  half8 y1 = *(const half8*)(z2h + (size_t)d*ZDIM + l*16 + 8);
  float dot = 0.f;
#pragma unroll
  for(int q=0;q<8;q++) dot = fmaf((float)x0[q], (float)y0[q], dot);
#pragma unroll
  for(int q=0;q<8;q++) dot = fmaf((float)x1[q], (float)y1[q], dot);
#pragma unroll
  for(int off=1; off<16; off<<=1) dot += __shfl_xor(dot, off, 64);
  if(l==0){
    float ds = dsum[s] - PAD_J;
    float P  = exp2f(dot)/ds * inv_nb[s]*inv_nb[d];
    float z  = (P - scal[0])*scal[1];
    float p12 = 1.f/(1.f + exp2f(-z*LOG2E));
    float eii = exp2f(sii[s]);
    float c5  = fabsf(eii/ds - 1.f)*inv_nb[s]*inv_nb[d];
    float z5  = (c5 - scal[2])*scal[3];
    float p5  = 1.f/(1.f + exp2f(-z5*LOG2E));
    unsigned key  = (unsigned)s*10000u + (unsigned)d;
    unsigned slot = (key*2654435761u) & HMASK;
    while(hkey[slot] != key) slot = (slot+1) & HMASK;
    ew[e] = 0.5f*(p5 + p12) * (float)hcnt[slot];
  }
}

// ---------- GCN weighted dst-degree ----------
__global__ void k_degw(const int* __restrict__ dst, const float* __restrict__ ew,
                       float* __restrict__ degw){
  int e = blockIdx.x*blockDim.x + threadIdx.x;
  if(e < N_EDGES) atomicAdd(&degw[dst[e]], ew[e]);
}

// ---------- cast fp32 -> fp16 with zero row padding ----------
__global__ void k_cast_pad(const float* __restrict__ A, _Float16* __restrict__ Ah, int M, int K){
  size_t t = (size_t)blockIdx.x*256 + threadIdx.x;
  size_t total = (size_t)NPAD*K/8;
  if(t >= total) return;
  size_t base = t*8;
  int row = (int)(base / (size_t)K);
  half8 o;
  if(row < M){
    float4 v0 = *(const float4*)(A + base);
    float4 v1 = *(const float4*)(A + base + 4);
    o[0]=(_Float16)v0.x; o[1]=(_Float16)v0.y; o[2]=(_Float16)v0.z; o[3]=(_Float16)v0.w;
    o[4]=(_Float16)v1.x; o[5]=(_Float16)v1.y; o[6]=(_Float16)v1.z; o[7]=(_Float16)v1.w;
  } else {
#pragma unroll
    for(int q=0;q<8;q++) o[q]=(_Float16)0.f;
  }
  *(half8*)(Ah + base) = o;
}

// ---------- transpose + cast: WT[n][k] = (fp16)W[k][n] ----------
__global__ void k_transpose_h(const float* __restrict__ W, _Float16* __restrict__ WT, int K, int N){
  __shared__ float t[32][33];
  int bx = blockIdx.x*32, by = blockIdx.y*32;
  int tx = threadIdx.x, ty = threadIdx.y;       // 32 x 8
  for(int r=ty; r<32; r+=8) t[r][tx] = W[(size_t)(by+r)*N + bx+tx];
  __syncthreads();
  for(int r=ty; r<32; r+=8) WT[(size_t)(bx+r)*K + by+tx] = (_Float16)t[tx][r];
}

// ---------- MFMA fp16 GEMM, 64x64 tiles: C[NPAD,Nc](fp16) = Ah[NPAD,K] @ BT[Nc,K]^T ----------
__launch_bounds__(256, 4)
__global__ void k_gemm_h(const _Float16* __restrict__ Ah, const _Float16* __restrict__ BT,
                         _Float16* __restrict__ C, int K, int Nc){
  __shared__ _Float16 As[64*64];   // 8 KB, row=128B, granule-swizzled
  __shared__ _Float16 Bs[64*64];   // 8 KB
  const int tid  = threadIdx.x;
  const int lane = tid & 63, w = tid >> 6;
  const int wr = w >> 1, wc = w & 1;
  const int l15 = lane & 15, l4 = lane >> 4;
  const int i0 = blockIdx.x * 64;
  const int n0 = blockIdx.y * 64;

  f32x4 acc[2][2];
#pragma unroll
  for(int a=0;a<2;a++)
#pragma unroll
    for(int b=0;b<2;b++) acc[a][b] = (f32x4){0.f,0.f,0.f,0.f};

  uint4 areg[2], brg[2];
#pragma unroll
  for(int q=0;q<2;q++){
    int g = tid + q*256;
    areg[q] = *(const uint4*)(Ah + (size_t)(i0 + (g>>3))*K + (g&7)*8);
    brg[q]  = *(const uint4*)(BT + (size_t)(n0 + (g>>3))*K + (g&7)*8);
  }

  for(int kc=0; kc<K; kc+=64){
    __syncthreads();
#pragma unroll
    for(int q=0;q<2;q++){
      int g = tid + q*256;
      int row = g>>3, cg = g&7;
      *(uint4*)((char*)As + row*128 + ((cg ^ (row&7))<<4)) = areg[q];
      *(uint4*)((char*)Bs + row*128 + ((cg ^ (row&7))<<4)) = brg[q];
    }
    if(kc + 64 < K){
#pragma unroll
      for(int q=0;q<2;q++){
        int g = tid + q*256;
        areg[q] = *(const uint4*)(Ah + (size_t)(i0 + (g>>3))*K + kc + 64 + (g&7)*8);
        brg[q]  = *(const uint4*)(BT + (size_t)(n0 + (g>>3))*K + kc + 64 + (g&7)*8);
      }
    }
    __syncthreads();
#pragma unroll
    for(int ksl=0; ksl<2; ++ksl){
      half8 af[2], bf[2];
#pragma unroll
      for(int mf=0; mf<2; ++mf){
        int r = wr*32 + mf*16 + l15;
        af[mf] = *(const half8*)((const char*)As + r*128 + (((ksl*4 + l4) ^ (r&7))<<4));
      }
#pragma unroll
      for(int nf=0; nf<2; ++nf){
        int r = wc*32 + nf*16 + l15;
        bf[nf] = *(const half8*)((const char*)Bs + r*128 + (((ksl*4 + l4) ^ (r&7))<<4));
      }
#pragma unroll
      for(int mf=0; mf<2; ++mf)
#pragma unroll
        for(int nf=0; nf<2; ++nf)
          acc[mf][nf] = __builtin_amdgcn_mfma_f32_16x16x32_f16(af[mf], bf[nf], acc[mf][nf], 0, 0, 0);
    }
  }
#pragma unroll
  for(int mf=0; mf<2; ++mf)
#pragma unroll
    for(int nf=0; nf<2; ++nf){
      int col = n0 + wc*32 + nf*16 + l15;
#pragma unroll
      for(int rg=0; rg<4; ++rg){
        int rowi = i0 + wr*32 + mf*16 + l4*4 + rg;
        C[(size_t)rowi*Nc + col] = (_Float16)acc[mf][nf][rg];
      }
    }
}

// ---------- CSR by dst ----------
__global__ void k_scan(const int* __restrict__ cnt, int* __restrict__ rowptr){
  __shared__ int part[1024];
  const int PER = 10;
  int tid = threadIdx.x;
  int base = tid*PER;
  int loc[PER];
  int s=0;
#pragma unroll
  for(int q=0;q<PER;q++){ int idx=base+q; int v=(idx<N_NODES)?cnt[idx]:0; loc[q]=v; s+=v; }
  part[tid]=s; __syncthreads();
  for(int off=1; off<1024; off<<=1){
    int v = (tid>=off) ? part[tid-off] : 0;
    __syncthreads();
    part[tid] += v;
    __syncthreads();
  }
  int run = (tid>0) ? part[tid-1] : 0;
#pragma unroll
  for(int q=0;q<PER;q++){ int idx=base+q; if(idx<N_NODES) rowptr[idx]=run; run+=loc[q]; }
  if(tid==1023) rowptr[N_NODES]=part[1023];
}
// fill CSR with pre-combined weights: scsr = src, wcsr = rsqrt(1+degw[src])*ew
__global__ void k_fill2(const int* __restrict__ dst, const int* __restrict__ src,
                        const float* __restrict__ ew, const float* __restrict__ degw,
                        const int* __restrict__ rowptr, int* __restrict__ fill,
                        int* __restrict__ scsr, float* __restrict__ wcsr){
  int e = blockIdx.x*blockDim.x + threadIdx.x;
  if(e >= N_EDGES) return;
  int d = dst[e];
  int pos = atomicAdd(&fill[d], 1);
  int idx = rowptr[d] + pos;
  int s = src[e];
  scsr[idx] = s;
  wcsr[idx] = ew[e]*rsqrtf(1.f + degw[s]);
}

// ---------- GCN aggregation, LDS-staged CSR row + 4x unrolled gathers ----------
template<int F, typename OutT>
__global__ void k_agg2(const _Float16* __restrict__ hw, const float* __restrict__ bias,
                       const int* __restrict__ rowptr, const int* __restrict__ scsr,
                       const float* __restrict__ wcsr, const float* __restrict__ degw,
                       OutT* __restrict__ out){
  const int v = blockIdx.x;
  const int tid = threadIdx.x;          // F/4 threads
  const int NT = F/4;
  __shared__ int   ss[256];
  __shared__ float sw[256];
  const half4* hp = (const half4*)hw;
  float dv = rsqrtf(1.f + degw[v]);
  half4 hs = hp[(size_t)v*NT + tid];
  float a0 = dv*(float)hs[0], a1 = dv*(float)hs[1], a2 = dv*(float)hs[2], a3 = dv*(float)hs[3];
  int b = rowptr[v], e = rowptr[v+1];
  for(int base=b; base<e; base+=256){
    int m = min(256, e-base);
    __syncthreads();
    for(int t=tid; t<m; t+=NT){ ss[t]=scsr[base+t]; sw[t]=wcsr[base+t]; }
    __syncthreads();
    int t=0;
    for(; t+4<=m; t+=4){
      int s0=ss[t], s1=ss[t+1], s2=ss[t+2], s3=ss[t+3];
      float w0=sw[t], w1=sw[t+1], w2=sw[t+2], w3=sw[t+3];
      half4 h0 = hp[(size_t)s0*NT + tid];
      half4 h1 = hp[(size_t)s1*NT + tid];
      half4 h2 = hp[(size_t)s2*NT + tid];
      half4 h3 = hp[(size_t)s3*NT + tid];
      a0 += w0*(float)h0[0] + w1*(float)h1[0] + w2*(float)h2[0] + w3*(float)h3[0];
      a1 += w0*(float)h0[1] + w1*(float)h1[1] + w2*(float)h2[1] + w3*(float)h3[1];
      a2 += w0*(float)h0[2] + w1*(float)h1[2] + w2*(float)h2[2] + w3*(float)h3[2];
      a3 += w0*(float)h0[3] + w1*(float)h1[3] + w2*(float)h2[3] + w3*(float)h3[3];
    }
    for(; t<m; ++t){
      int s=ss[t]; float wq=sw[t];
      half4 h = hp[(size_t)s*NT + tid];
      a0 += wq*(float)h[0]; a1 += wq*(float)h[1]; a2 += wq*(float)h[2]; a3 += wq*(float)h[3];
    }
  }
  int f0 = tid*4;
  float r0 = fmaxf(dv*a0 + bias[f0  ], 0.f);
  float r1 = fmaxf(dv*a1 + bias[f0+1], 0.f);
  float r2 = fmaxf(dv*a2 + bias[f0+2], 0.f);
  float r3 = fmaxf(dv*a3 + bias[f0+3], 0.f);
  if constexpr (sizeof(OutT)==2){
    half4 o; o[0]=(_Float16)r0; o[1]=(_Float16)r1; o[2]=(_Float16)r2; o[3]=(_Float16)r3;
    *(half4*)(out + (size_t)v*F + f0) = o;
  } else {
    float4 o = make_float4(r0,r1,r2,r3);
    *(float4*)(out + (size_t)v*F + f0) = o;
  }
}

extern "C" void kernel_launch(void* const* d_in, const int* in_sizes, int n_in,
                              void* d_out, int out_size, void* d_ws, size_t ws_size,
                              hipStream_t stream){
  const float* x   = (const float*)d_in[0];
  const float* pz1 = (const float*)d_in[1];
  const float* pz2 = (const float*)d_in[2];
  const float* W0  = (const float*)d_in[3];
  const float* b0  = (const float*)d_in[4];
  const float* W1  = (const float*)d_in[5];
  const float* b1  = (const float*)d_in[6];
  const int*   ei  = (const int*)d_in[7];
  const int* src = ei;
  const int* dst = ei + N_EDGES;
  float* out = (float*)d_out;

  char* ws = (char*)d_ws;
  size_t off = 0;
  auto alloc = [&](size_t bytes)->char*{
    char* p = ws + off;
    off += (bytes + 255) & ~(size_t)255;
    return p;
  };

  _Float16* z1h  = (_Float16*)alloc((size_t)NPAD*ZDIM*2);   // reused as hw1h after k_edge_w
  _Float16* z2h  = (_Float16*)alloc((size_t)NPAD*ZDIM*2);
  _Float16* xh   = (_Float16*)alloc((size_t)NPAD*512*2);
  _Float16* hw0h = (_Float16*)alloc((size_t)NPAD*512*2);
  _Float16* h1h  = (_Float16*)alloc((size_t)NPAD*512*2);
  _Float16* W0T  = (_Float16*)alloc((size_t)512*512*2);
  _Float16* W1T  = (_Float16*)alloc((size_t)256*512*2);
  float* parts   = (float*)alloc(3*PSTRIDE*4);              // 9.6 MB
  float* ew      = (float*)alloc((size_t)N_EDGES*4);
  float* dsum    = (float*)alloc(NPAD*4);
  float* t1s     = (float*)alloc(NPAD*4);
  float* t2s     = (float*)alloc(NPAD*4);
  float* inv_nb  = (float*)alloc(NPAD*4);
  float* sii     = (float*)alloc(NPAD*4);
  float* degw    = (float*)alloc(NPAD*4);
  float* scal    = (float*)alloc(256);
  int* deg       = (int*)alloc(NPAD*4);
  int* cnt       = (int*)alloc(NPAD*4);
  int* rowptr    = (int*)alloc((NPAD+1)*4);
  int* fill      = (int*)alloc(NPAD*4);
  int* scsr      = (int*)alloc((size_t)N_EDGES*4);
  float* wcsr    = (float*)alloc((size_t)N_EDGES*4);
  unsigned* hkey = (unsigned*)alloc((size_t)HCAP*4);
  unsigned* hcnt = (unsigned*)alloc((size_t)HCAP*4);
  _Float16* hw1h = z1h;     // [NPAD,256] fp16, z1h dead after k_edge_w

  hipMemsetAsync(deg,  0, NPAD*4, stream);
  hipMemsetAsync(cnt,  0, NPAD*4, stream);
  hipMemsetAsync(fill, 0, NPAD*4, stream);
  hipMemsetAsync(degw, 0, NPAD*4, stream);
  hipMemsetAsync(hkey, 0xFF, (size_t)HCAP*4, stream);
  hipMemsetAsync(hcnt, 0,    (size_t)HCAP*4, stream);

  const int EB = (N_EDGES+255)/256;

  // similarity pipeline (z1 pre-scaled by 2*log2e)
  k_l2norm2<<<dim3(NPAD,2), 256, 0, stream>>>(pz1, pz2, z1h, z2h, N_NODES);
  k_edge_pre<<<EB, 256, 0, stream>>>(src, dst, deg, cnt, hkey, hcnt);
  k_inv_nb<<<(NPAD+255)/256, 256, 0, stream>>>(deg, inv_nb);
  k_diag_h<<<(N_NODES*64+255)/256, 256, 0, stream>>>(z1h, z2h, sii);
  k_stats_mfma<<<79*80, 256, 0, stream>>>(z1h, z2h, inv_nb, parts);
  k_redparts<<<(NPAD+255)/256, 256, 0, stream>>>(parts, dsum, t1s, t2s);
  k_finalize<<<1, 256, 0, stream>>>(dsum, t1s, t2s, inv_nb, sii, scal);
  k_edge_w<<<(N_EDGES*16)/256, 256, 0, stream>>>(src, dst, z1h, z2h, dsum, inv_nb, sii, scal, hkey, hcnt, ew);

  // GCN prep
  k_cast_pad<<<(int)(((size_t)NPAD*512/8 + 255)/256), 256, 0, stream>>>(x, xh, N_NODES, 512);
  k_transpose_h<<<dim3(16,16), dim3(32,8), 0, stream>>>(W0, W0T, 512, 512);
  k_transpose_h<<<dim3(8,16),  dim3(32,8), 0, stream>>>(W1, W1T, 512, 256);

  k_degw<<<EB, 256, 0, stream>>>(dst, ew, degw);
  k_scan<<<1, 1024, 0, stream>>>(cnt, rowptr);
  k_fill2<<<EB, 256, 0, stream>>>(dst, src, ew, degw, rowptr, fill, scsr, wcsr);

  // layer 1: hw0h = fp16(xh @ W0); h1h = fp16(relu(agg(hw0h) + b0))
  k_gemm_h<<<dim3(158, 8), 256, 0, stream>>>(xh, W0T, hw0h, 512, 512);
  k_agg2<512,_Float16><<<N_NODES, 128, 0, stream>>>(hw0h, b0, rowptr, scsr, wcsr, degw, h1h);
  // layer 2: hw1h = fp16(h1h @ W1); out = relu(agg(hw1h) + b1)
  k_gemm_h<<<dim3(158, 4), 256, 0, stream>>>(h1h, W1T, hw1h, 512, 256);
  k_agg2<256,float><<<N_NODES, 64, 0, stream>>>(hw1h, b1, rowptr, scsr, wcsr, degw, out);

  (void)in_sizes; (void)n_in; (void)out_size; (void)ws_size;
}

// Round 6
// 436.106 us; speedup vs baseline: 4.3667x; 1.1508x over previous
//
#include <hip/hip_runtime.h>
#include <math.h>

#define N_NODES 10000
#define N_EDGES 320000
#define ZDIM    256
#define NPAD    10112          // 79 * 128 = 158 * 64
#define PAD_J   112.0f         // padded cols contribute exp2(0)=1 to row sums
#define HCAP    (1u<<19)
#define HMASK   (HCAP-1u)
#define HEMPTY  0xFFFFFFFFu
#define TWO_LOG2E 2.8853900817779268f   // z1 pre-scale: exp(dot/0.5) = exp2(dot*2log2e)
#define LOG2E     1.4426950408889634f
#define NJB 79
#define PSTRIDE ((size_t)NJB*NPAD)

typedef _Float16 half8 __attribute__((ext_vector_type(8)));
typedef _Float16 half4 __attribute__((ext_vector_type(4)));
typedef float f32x4 __attribute__((ext_vector_type(4)));

__device__ __forceinline__ float wave_red_sum64(float v){
#pragma unroll
  for(int off=1; off<64; off<<=1) v += __shfl_xor(v, off, 64);
  return v;
}

// ---------- row L2 normalize (both arrays, one launch) -> fp16, z1 pre-scaled ----------
__global__ void k_l2norm2(const float* __restrict__ z1, const float* __restrict__ z2,
                          _Float16* __restrict__ o1, _Float16* __restrict__ o2, int rows){
  int r = blockIdx.x;
  int which = blockIdx.y;
  const float* z = which ? z2 : z1;
  _Float16* o = which ? o2 : o1;
  float mul = which ? 1.0f : TWO_LOG2E;
  int t = threadIdx.x;
  float v = (r < rows) ? z[(size_t)r*ZDIM + t] : 0.f;
  float s = wave_red_sum64(v*v);
  __shared__ float red[4];
  int lane = t & 63, wid = t >> 6;
  if(lane==0) red[wid]=s;
  __syncthreads();
  float tot = red[0]+red[1]+red[2]+red[3];
  float scale = mul/fmaxf(sqrtf(tot), 1e-12f);
  o[(size_t)r*ZDIM + t] = (_Float16)(v*scale);
}

// ---------- fused edge pass: src-degree, dst-degree, duplicate hash ----------
__global__ void k_edge_pre(const int* __restrict__ src, const int* __restrict__ dst,
                           int* __restrict__ deg, int* __restrict__ cnt,
                           unsigned* __restrict__ hkey, unsigned* __restrict__ hcnt){
  int e = blockIdx.x*blockDim.x + threadIdx.x;
  if(e >= N_EDGES) return;
  int s = src[e], d = dst[e];
  atomicAdd(&deg[s], 1);
  atomicAdd(&cnt[d], 1);
  unsigned key = (unsigned)s*10000u + (unsigned)d;
  unsigned slot = (key * 2654435761u) & HMASK;
  while(true){
    unsigned old = atomicCAS(&hkey[slot], HEMPTY, key);
    if(old==HEMPTY || old==key){ atomicAdd(&hcnt[slot], 1u); break; }
    slot = (slot+1) & HMASK;
  }
}
__global__ void k_inv_nb(const int* __restrict__ deg, float* __restrict__ inv_nb){
  int i = blockIdx.x*blockDim.x + threadIdx.x;
  if(i < NPAD) inv_nb[i] = (i < N_NODES) ? 1.f/sqrtf((float)deg[i] + 1.f) : 0.f;
}

// ---------- diagonal S_ii (scaled: z1h carries 2log2e) ----------
__global__ void k_diag_h(const _Float16* __restrict__ z1h, const _Float16* __restrict__ z2h,
                         float* __restrict__ sii){
  int gt = blockIdx.x*blockDim.x + threadIdx.x;
  int n = gt >> 6, lane = gt & 63;
  if(n >= N_NODES) return;
  half4 x = *(const half4*)(z1h + (size_t)n*ZDIM + lane*4);
  half4 y = *(const half4*)(z2h + (size_t)n*ZDIM + lane*4);
  float s = (float)x[0]*(float)y[0] + (float)x[1]*(float)y[1]
          + (float)x[2]*(float)y[2] + (float)x[3]*(float)y[3];
  s = wave_red_sum64(s);
  if(lane==0) sii[n] = s;
}

// ---------- MFMA fp16 streaming stats: XCD-chunked grid, 2-phase dbuf pipeline ----------
// grid 79x80 linear; xcd = bid&7 owns 10 j-panels (L2-resident).
// dbuf LDS + raw barriers + issue-early/drain-late staging (guide T3 minimum 2-phase).
__launch_bounds__(256, 2)
__global__ void k_stats_mfma(const _Float16* __restrict__ z1h, const _Float16* __restrict__ z2h,
                             const float* __restrict__ inv_nb, float* __restrict__ parts){
  __shared__ _Float16 As[2][128*64];   // 2 x 16 KB
  __shared__ _Float16 Bs[2][128*64];   // 2 x 16 KB
  __shared__ float sred[2][3][512];    // 12 KB
  const int bid = blockIdx.x;
  const int xcd = bid & 7, c = bid >> 3;
  const int ib = c / 10, jj = c - ib*10;
  const int jb = xcd*10 + jj;
  if(jb >= NJB) return;
  const int tid  = threadIdx.x;
  const int lane = tid & 63, w = tid >> 6;
  const int wr = w >> 1, wc = w & 1;
  const int l15 = lane & 15, l4 = lane >> 4;
  const int i0 = ib * 128;
  const int n0 = jb * 128;

  f32x4 acc[4][4];
#pragma unroll
  for(int a=0;a<4;a++)
#pragma unroll
    for(int b=0;b<4;b++) acc[a][b] = (f32x4){0.f,0.f,0.f,0.f};

  auto stage = [&](int buf, int kc){
#pragma unroll
    for(int q=0;q<4;q++){
      int s = w*256 + q*64 + lane;         // linear 16B slot
      int row = s >> 3;
      int cg  = (s & 7) ^ (row & 7);       // inverse swizzle on source
      __builtin_amdgcn_global_load_lds(
        (const __attribute__((address_space(1))) unsigned*)(z1h + (size_t)(i0+row)*ZDIM + kc + cg*8),
        (__attribute__((address_space(3))) unsigned*)(&As[buf][(w*256 + q*64)*8]),
        16, 0, 0);
      __builtin_amdgcn_global_load_lds(
        (const __attribute__((address_space(1))) unsigned*)(z2h + (size_t)(n0+row)*ZDIM + kc + cg*8),
        (__attribute__((address_space(3))) unsigned*)(&Bs[buf][(w*256 + q*64)*8]),
        16, 0, 0);
    }
  };
  auto compute = [&](int buf){
#pragma unroll
    for(int ksl=0; ksl<2; ++ksl){
      half8 af[4], bf[4];
#pragma unroll
      for(int mf=0; mf<4; ++mf){
        int r = wr*64 + mf*16 + l15;
        af[mf] = *(const half8*)((const char*)As[buf] + r*128 + (((ksl*4 + l4) ^ (r&7))<<4));
      }
#pragma unroll
      for(int nf=0; nf<4; ++nf){
        int r = wc*64 + nf*16 + l15;
        bf[nf] = *(const half8*)((const char*)Bs[buf] + r*128 + (((ksl*4 + l4) ^ (r&7))<<4));
      }
#pragma unroll
      for(int mf=0; mf<4; ++mf)
#pragma unroll
        for(int nf=0; nf<4; ++nf)
          acc[mf][nf] = __builtin_amdgcn_mfma_f32_16x16x32_f16(af[mf], bf[nf], acc[mf][nf], 0, 0, 0);
    }
  };

  // prologue
  stage(0, 0);
  asm volatile("s_waitcnt vmcnt(0)" ::: "memory");
  __builtin_amdgcn_s_barrier();
  // 2-phase main loop: issue next-tile loads, compute current, drain, barrier
#pragma unroll
  for(int kc64=0; kc64<3; ++kc64){
    stage((kc64+1)&1, (kc64+1)*64);
    compute(kc64&1);
    asm volatile("s_waitcnt vmcnt(0)" ::: "memory");
    __builtin_amdgcn_s_barrier();
  }
  compute(1);                              // last k-step, no prefetch

  // epilogue: e = exp2(acc), per-row d/t1/t2; 2-step shuffle + LDS combine
  float inbv[4];
#pragma unroll
  for(int nf=0;nf<4;nf++) inbv[nf] = inv_nb[n0 + wc*64 + nf*16 + l15];

  float dacc[4][4], t1a[4][4], t2a[4][4];
#pragma unroll
  for(int mf=0; mf<4; ++mf)
#pragma unroll
    for(int rg=0; rg<4; ++rg){ dacc[mf][rg]=0.f; t1a[mf][rg]=0.f; t2a[mf][rg]=0.f; }

#pragma unroll
  for(int mf=0; mf<4; ++mf)
#pragma unroll
    for(int nf=0; nf<4; ++nf){
      float inb = inbv[nf], inb2 = inb*inb;
#pragma unroll
      for(int rg=0; rg<4; ++rg){
        float e = exp2f(acc[mf][nf][rg]);
        dacc[mf][rg] += e;
        t1a[mf][rg] = fmaf(e, inb, t1a[mf][rg]);
        t2a[mf][rg] = fmaf(e*e, inb2, t2a[mf][rg]);
      }
    }

#pragma unroll
  for(int mf=0; mf<4; ++mf)
#pragma unroll
    for(int rg=0; rg<4; ++rg){
      float d = dacc[mf][rg], t1 = t1a[mf][rg], t2 = t2a[mf][rg];
      d  += __shfl_xor(d, 1, 64);  d  += __shfl_xor(d, 2, 64);
      t1 += __shfl_xor(t1,1, 64);  t1 += __shfl_xor(t1,2, 64);
      t2 += __shfl_xor(t2,1, 64);  t2 += __shfl_xor(t2,2, 64);
      if((l15&3)==0){
        int il = wr*64 + mf*16 + l4*4 + rg;
        int sl = il*4 + (l15>>2);
        sred[wc][0][sl] = d;
        sred[wc][1][sl] = t1;
        sred[wc][2][sl] = t2;
      }
    }
  __syncthreads();
  if(tid < 128){
#pragma unroll
    for(int s=0;s<3;s++){
      float4 a = *(const float4*)&sred[0][s][tid*4];
      float4 b = *(const float4*)&sred[1][s][tid*4];
      parts[(size_t)s*PSTRIDE + (size_t)jb*NPAD + i0 + tid] =
        (a.x+a.y)+(a.z+a.w)+(b.x+b.y)+(b.z+b.w);
    }
  }
}

// ---------- reduce partials over jb ----------
__global__ void k_redparts(const float* __restrict__ parts, float* __restrict__ dsum,
                           float* __restrict__ t1s, float* __restrict__ t2s){
  int i = blockIdx.x*256 + threadIdx.x;
  if(i >= NPAD) return;
  float a=0.f, b=0.f, c=0.f;
  for(int j=0;j<NJB;j++){
    a += parts[(size_t)j*NPAD + i];
    b += parts[PSTRIDE + (size_t)j*NPAD + i];
    c += parts[2*PSTRIDE + (size_t)j*NPAD + i];
  }
  dsum[i]=a; t1s[i]=b; t2s[i]=c;
}

// ---------- global mean/std of P and P5 (fp64 reduce) ----------
__global__ void k_finalize(const float* __restrict__ dsum, const float* __restrict__ t1s,
                           const float* __restrict__ t2s, const float* __restrict__ inv_nb,
                           const float* __restrict__ sii, float* __restrict__ scal){
  int tid = threadIdx.x;
  double A=0,B=0,S1=0,S2=0,Snb=0,Snb2=0;
  for(int i=tid;i<N_NODES;i+=256){
    float d   = dsum[i] - PAD_J;
    float inb = inv_nb[i];
    float t1  = t1s[i], t2 = t2s[i];
    A += (double)(t1*inb/d);
    B += (double)((t2*inb*inb)/(d*d));
    float eii = exp2f(sii[i]);
    float ci  = fabsf(eii/d - 1.f)*inb;
    S1 += (double)ci; S2 += (double)ci*(double)ci;
    Snb += (double)inb; Snb2 += (double)inb*(double)inb;
  }
  __shared__ double red[256];
  double vals[6]={A,B,S1,S2,Snb,Snb2};
  double out[6];
  for(int v=0;v<6;v++){
    red[tid]=vals[v]; __syncthreads();
    for(int off=128;off;off>>=1){ if(tid<off) red[tid]+=red[tid+off]; __syncthreads(); }
    out[v]=red[0]; __syncthreads();
  }
  if(tid==0){
    double M = (double)N_NODES*(double)N_NODES;
    double mean  = out[0]/M;
    double var   = (out[1] - out[0]*out[0]/M)/(M-1.0);
    double sp5   = out[2]*out[4];
    double mean5 = sp5/M;
    double var5  = (out[3]*out[5] - sp5*sp5/M)/(M-1.0);
    scal[0]=(float)mean;  scal[1]=(float)(1.0/sqrt(var));
    scal[2]=(float)mean5; scal[3]=(float)(1.0/sqrt(var5));
  }
}

// ---------- per-edge weight (16 lanes/edge) + fused weighted dst-degree ----------
__global__ void k_edge_w(const int* __restrict__ src, const int* __restrict__ dst,
                         const _Float16* __restrict__ z1h, const _Float16* __restrict__ z2h,
                         const float* __restrict__ dsum, const float* __restrict__ inv_nb,
                         const float* __restrict__ sii, const float* __restrict__ scal,
                         const unsigned* __restrict__ hkey, const unsigned* __restrict__ hcnt,
                         float* __restrict__ ew, float* __restrict__ degw){
  int gt = blockIdx.x*blockDim.x + threadIdx.x;
  int e = gt >> 4, l = gt & 15;
  if(e >= N_EDGES) return;
  int s = src[e], d = dst[e];
  half8 x0 = *(const half8*)(z1h + (size_t)s*ZDIM + l*16);
  half8 x1 = *(const half8*)(z1h + (size_t)s*ZDIM + l*16 + 8);
  half8 y0 = *(const half8*)(z2h + (size_t)d*ZDIM + l*16);
  half8 y1 = *(const half8*)(z2h + (size_t)d*ZDIM + l*16 + 8);
  float dot = 0.f;
#pragma unroll
  for(int q=0;q<8;q++) dot = fmaf((float)x0[q], (float)y0[q], dot);
#pragma unroll
  for(int q=0;q<8;q++) dot = fmaf((float)x1[q], (float)y1[q], dot);
#pragma unroll
  for(int off=1; off<16; off<<=1) dot += __shfl_xor(dot, off, 64);
  if(l==0){
    float ds = dsum[s] - PAD_J;
    float P  = exp2f(dot)/ds * inv_nb[s]*inv_nb[d];
    float z  = (P - scal[0])*scal[1];
    float p12 = 1.f/(1.f + exp2f(-z*LOG2E));
    float eii = exp2f(sii[s]);
    float c5  = fabsf(eii/ds - 1.f)*inv_nb[s]*inv_nb[d];
    float z5  = (c5 - scal[2])*scal[3];
    float p5  = 1.f/(1.f + exp2f(-z5*LOG2E));
    unsigned key  = (unsigned)s*10000u + (unsigned)d;
    unsigned slot = (key*2654435761u) & HMASK;
    while(hkey[slot] != key) slot = (slot+1) & HMASK;
    float wv = 0.5f*(p5 + p12) * (float)hcnt[slot];
    ew[e] = wv;
    atomicAdd(&degw[d], wv);
  }
}

// ---------- cast fp32 -> fp16 with zero row padding ----------
__global__ void k_cast_pad(const float* __restrict__ A, _Float16* __restrict__ Ah, int M, int K){
  size_t t = (size_t)blockIdx.x*256 + threadIdx.x;
  size_t total = (size_t)NPAD*K/8;
  if(t >= total) return;
  size_t base = t*8;
  int row = (int)(base / (size_t)K);
  half8 o;
  if(row < M){
    float4 v0 = *(const float4*)(A + base);
    float4 v1 = *(const float4*)(A + base + 4);
    o[0]=(_Float16)v0.x; o[1]=(_Float16)v0.y; o[2]=(_Float16)v0.z; o[3]=(_Float16)v0.w;
    o[4]=(_Float16)v1.x; o[5]=(_Float16)v1.y; o[6]=(_Float16)v1.z; o[7]=(_Float16)v1.w;
  } else {
#pragma unroll
    for(int q=0;q<8;q++) o[q]=(_Float16)0.f;
  }
  *(half8*)(Ah + base) = o;
}

// ---------- transpose + cast: WT[n][k] = (fp16)W[k][n] ----------
__global__ void k_transpose_h(const float* __restrict__ W, _Float16* __restrict__ WT, int K, int N){
  __shared__ float t[32][33];
  int bx = blockIdx.x*32, by = blockIdx.y*32;
  int tx = threadIdx.x, ty = threadIdx.y;       // 32 x 8
  for(int r=ty; r<32; r+=8) t[r][tx] = W[(size_t)(by+r)*N + bx+tx];
  __syncthreads();
  for(int r=ty; r<32; r+=8) WT[(size_t)(bx+r)*K + by+tx] = (_Float16)t[tx][r];
}

// ---------- MFMA fp16 GEMM, 64x64 tiles, 2-phase gl_lds pipeline ----------
__launch_bounds__(256, 4)
__global__ void k_gemm_h(const _Float16* __restrict__ Ah, const _Float16* __restrict__ BT,
                         _Float16* __restrict__ C, int K, int Nc){
  __shared__ _Float16 As[2][64*64];   // 2 x 8 KB
  __shared__ _Float16 Bs[2][64*64];   // 2 x 8 KB
  const int tid  = threadIdx.x;
  const int lane = tid & 63, w = tid >> 6;
  const int wr = w >> 1, wc = w & 1;
  const int l15 = lane & 15, l4 = lane >> 4;
  const int i0 = blockIdx.x * 64;
  const int n0 = blockIdx.y * 64;

  f32x4 acc[2][2];
#pragma unroll
  for(int a=0;a<2;a++)
#pragma unroll
    for(int b=0;b<2;b++) acc[a][b] = (f32x4){0.f,0.f,0.f,0.f};

  auto stage = [&](int buf, int kc){
#pragma unroll
    for(int q=0;q<2;q++){
      int s = w*128 + q*64 + lane;
      int row = s >> 3;
      int cg  = (s & 7) ^ (row & 7);
      __builtin_amdgcn_global_load_lds(
        (const __attribute__((address_space(1))) unsigned*)(Ah + (size_t)(i0+row)*K + kc + cg*8),
        (__attribute__((address_space(3))) unsigned*)(&As[buf][(w*128 + q*64)*8]),
        16, 0, 0);
      __builtin_amdgcn_global_load_lds(
        (const __attribute__((address_space(1))) unsigned*)(BT + (size_t)(n0+row)*K + kc + cg*8),
        (__attribute__((address_space(3))) unsigned*)(&Bs[buf][(w*128 + q*64)*8]),
        16, 0, 0);
    }
  };
  auto compute = [&](int buf){
#pragma unroll
    for(int ksl=0; ksl<2; ++ksl){
      half8 af[2], bf[2];
#pragma unroll
      for(int mf=0; mf<2; ++mf){
        int r = wr*32 + mf*16 + l15;
        af[mf] = *(const half8*)((const char*)As[buf] + r*128 + (((ksl*4 + l4) ^ (r&7))<<4));
      }
#pragma unroll
      for(int nf=0; nf<2; ++nf){
        int r = wc*32 + nf*16 + l15;
        bf[nf] = *(const half8*)((const char*)Bs[buf] + r*128 + (((ksl*4 + l4) ^ (r&7))<<4));
      }
#pragma unroll
      for(int mf=0; mf<2; ++mf)
#pragma unroll
        for(int nf=0; nf<2; ++nf)
          acc[mf][nf] = __builtin_amdgcn_mfma_f32_16x16x32_f16(af[mf], bf[nf], acc[mf][nf], 0, 0, 0);
    }
  };

  const int nk = K >> 6;
  stage(0, 0);
  asm volatile("s_waitcnt vmcnt(0)" ::: "memory");
  __builtin_amdgcn_s_barrier();
  for(int kc64=0; kc64<nk-1; ++kc64){
    stage((kc64+1)&1, (kc64+1)*64);
    compute(kc64&1);
    asm volatile("s_waitcnt vmcnt(0)" ::: "memory");
    __builtin_amdgcn_s_barrier();
  }
  compute((nk-1)&1);

#pragma unroll
  for(int mf=0; mf<2; ++mf)
#pragma unroll
    for(int nf=0; nf<2; ++nf){
      int col = n0 + wc*32 + nf*16 + l15;
#pragma unroll
      for(int rg=0; rg<4; ++rg){
        int rowi = i0 + wr*32 + mf*16 + l4*4 + rg;
        C[(size_t)rowi*Nc + col] = (_Float16)acc[mf][nf][rg];
      }
    }
}

// ---------- CSR by dst ----------
__global__ void k_scan(const int* __restrict__ cnt, int* __restrict__ rowptr){
  __shared__ int part[1024];
  const int PER = 10;
  int tid = threadIdx.x;
  int base = tid*PER;
  int loc[PER];
  int s=0;
#pragma unroll
  for(int q=0;q<PER;q++){ int idx=base+q; int v=(idx<N_NODES)?cnt[idx]:0; loc[q]=v; s+=v; }
  part[tid]=s; __syncthreads();
  for(int off=1; off<1024; off<<=1){
    int v = (tid>=off) ? part[tid-off] : 0;
    __syncthreads();
    part[tid] += v;
    __syncthreads();
  }
  int run = (tid>0) ? part[tid-1] : 0;
#pragma unroll
  for(int q=0;q<PER;q++){ int idx=base+q; if(idx<N_NODES) rowptr[idx]=run; run+=loc[q]; }
  if(tid==1023) rowptr[N_NODES]=part[1023];
}
// fill CSR with pre-combined weights: scsr = src, wcsr = rsqrt(1+degw[src])*ew
__global__ void k_fill2(const int* __restrict__ dst, const int* __restrict__ src,
                        const float* __restrict__ ew, const float* __restrict__ degw,
                        const int* __restrict__ rowptr, int* __restrict__ fill,
                        int* __restrict__ scsr, float* __restrict__ wcsr){
  int e = blockIdx.x*blockDim.x + threadIdx.x;
  if(e >= N_EDGES) return;
  int d = dst[e];
  int pos = atomicAdd(&fill[d], 1);
  int idx = rowptr[d] + pos;
  int s = src[e];
  scsr[idx] = s;
  wcsr[idx] = ew[e]*rsqrtf(1.f + degw[s]);
}

// ---------- GCN aggregation: direct broadcast reads, 8x unrolled gathers ----------
template<int F, typename OutT>
__global__ void k_agg2(const _Float16* __restrict__ hw, const float* __restrict__ bias,
                       const int* __restrict__ rowptr, const int* __restrict__ scsr,
                       const float* __restrict__ wcsr, const float* __restrict__ degw,
                       OutT* __restrict__ out){
  const int v = blockIdx.x;
  const int tid = threadIdx.x;          // F/4 threads
  const int NT = F/4;
  const half4* hp = (const half4*)hw;
  float dv = rsqrtf(1.f + degw[v]);
  half4 hs = hp[(size_t)v*NT + tid];
  float a0 = dv*(float)hs[0], a1 = dv*(float)hs[1], a2 = dv*(float)hs[2], a3 = dv*(float)hs[3];
  int b = rowptr[v], e = rowptr[v+1];
  int t = b;
  for(; t+8<=e; t+=8){
    int   sv[8]; float wv[8]; half4 hv[8];
#pragma unroll
    for(int q=0;q<8;q++){ sv[q]=scsr[t+q]; wv[q]=wcsr[t+q]; }
#pragma unroll
    for(int q=0;q<8;q++) hv[q] = hp[(size_t)sv[q]*NT + tid];
#pragma unroll
    for(int q=0;q<8;q++){
      a0 += wv[q]*(float)hv[q][0];
      a1 += wv[q]*(float)hv[q][1];
      a2 += wv[q]*(float)hv[q][2];
      a3 += wv[q]*(float)hv[q][3];
    }
  }
  for(; t<e; ++t){
    int s=scsr[t]; float wq=wcsr[t];
    half4 h = hp[(size_t)s*NT + tid];
    a0 += wq*(float)h[0]; a1 += wq*(float)h[1]; a2 += wq*(float)h[2]; a3 += wq*(float)h[3];
  }
  int f0 = tid*4;
  float r0 = fmaxf(dv*a0 + bias[f0  ], 0.f);
  float r1 = fmaxf(dv*a1 + bias[f0+1], 0.f);
  float r2 = fmaxf(dv*a2 + bias[f0+2], 0.f);
  float r3 = fmaxf(dv*a3 + bias[f0+3], 0.f);
  if constexpr (sizeof(OutT)==2){
    half4 o; o[0]=(_Float16)r0; o[1]=(_Float16)r1; o[2]=(_Float16)r2; o[3]=(_Float16)r3;
    *(half4*)(out + (size_t)v*F + f0) = o;
  } else {
    float4 o = make_float4(r0,r1,r2,r3);
    *(float4*)(out + (size_t)v*F + f0) = o;
  }
}

extern "C" void kernel_launch(void* const* d_in, const int* in_sizes, int n_in,
                              void* d_out, int out_size, void* d_ws, size_t ws_size,
                              hipStream_t stream){
  const float* x   = (const float*)d_in[0];
  const float* pz1 = (const float*)d_in[1];
  const float* pz2 = (const float*)d_in[2];
  const float* W0  = (const float*)d_in[3];
  const float* b0  = (const float*)d_in[4];
  const float* W1  = (const float*)d_in[5];
  const float* b1  = (const float*)d_in[6];
  const int*   ei  = (const int*)d_in[7];
  const int* src = ei;
  const int* dst = ei + N_EDGES;
  float* out = (float*)d_out;

  char* ws = (char*)d_ws;
  size_t off = 0;
  auto alloc = [&](size_t bytes)->char*{
    char* p = ws + off;
    off += (bytes + 255) & ~(size_t)255;
    return p;
  };

  _Float16* z1h  = (_Float16*)alloc((size_t)NPAD*ZDIM*2);   // reused as hw1h after k_edge_w
  _Float16* z2h  = (_Float16*)alloc((size_t)NPAD*ZDIM*2);
  _Float16* xh   = (_Float16*)alloc((size_t)NPAD*512*2);
  _Float16* hw0h = (_Float16*)alloc((size_t)NPAD*512*2);
  _Float16* h1h  = (_Float16*)alloc((size_t)NPAD*512*2);
  _Float16* W0T  = (_Float16*)alloc((size_t)512*512*2);
  _Float16* W1T  = (_Float16*)alloc((size_t)256*512*2);
  float* parts   = (float*)alloc(3*PSTRIDE*4);              // 9.6 MB
  float* ew      = (float*)alloc((size_t)N_EDGES*4);
  float* dsum    = (float*)alloc(NPAD*4);
  float* t1s     = (float*)alloc(NPAD*4);
  float* t2s     = (float*)alloc(NPAD*4);
  float* inv_nb  = (float*)alloc(NPAD*4);
  float* sii     = (float*)alloc(NPAD*4);
  float* degw    = (float*)alloc(NPAD*4);
  float* scal    = (float*)alloc(256);
  int* deg       = (int*)alloc(NPAD*4);
  int* cnt       = (int*)alloc(NPAD*4);
  int* rowptr    = (int*)alloc((NPAD+1)*4);
  int* fill      = (int*)alloc(NPAD*4);
  int* scsr      = (int*)alloc((size_t)N_EDGES*4);
  float* wcsr    = (float*)alloc((size_t)N_EDGES*4);
  unsigned* hkey = (unsigned*)alloc((size_t)HCAP*4);
  unsigned* hcnt = (unsigned*)alloc((size_t)HCAP*4);
  _Float16* hw1h = z1h;     // [NPAD,256] fp16, z1h dead after k_edge_w

  hipMemsetAsync(deg,  0, NPAD*4, stream);
  hipMemsetAsync(cnt,  0, NPAD*4, stream);
  hipMemsetAsync(fill, 0, NPAD*4, stream);
  hipMemsetAsync(degw, 0, NPAD*4, stream);
  hipMemsetAsync(hkey, 0xFF, (size_t)HCAP*4, stream);
  hipMemsetAsync(hcnt, 0,    (size_t)HCAP*4, stream);

  const int EB = (N_EDGES+255)/256;

  // similarity pipeline (z1 pre-scaled by 2*log2e)
  k_l2norm2<<<dim3(NPAD,2), 256, 0, stream>>>(pz1, pz2, z1h, z2h, N_NODES);
  k_edge_pre<<<EB, 256, 0, stream>>>(src, dst, deg, cnt, hkey, hcnt);
  k_inv_nb<<<(NPAD+255)/256, 256, 0, stream>>>(deg, inv_nb);
  k_diag_h<<<(N_NODES*64+255)/256, 256, 0, stream>>>(z1h, z2h, sii);
  k_stats_mfma<<<79*80, 256, 0, stream>>>(z1h, z2h, inv_nb, parts);
  k_redparts<<<(NPAD+255)/256, 256, 0, stream>>>(parts, dsum, t1s, t2s);
  k_finalize<<<1, 256, 0, stream>>>(dsum, t1s, t2s, inv_nb, sii, scal);
  k_edge_w<<<(N_EDGES*16)/256, 256, 0, stream>>>(src, dst, z1h, z2h, dsum, inv_nb, sii, scal, hkey, hcnt, ew, degw);

  // GCN prep
  k_cast_pad<<<(int)(((size_t)NPAD*512/8 + 255)/256), 256, 0, stream>>>(x, xh, N_NODES, 512);
  k_transpose_h<<<dim3(16,16), dim3(32,8), 0, stream>>>(W0, W0T, 512, 512);
  k_transpose_h<<<dim3(8,16),  dim3(32,8), 0, stream>>>(W1, W1T, 512, 256);

  k_scan<<<1, 1024, 0, stream>>>(cnt, rowptr);
  k_fill2<<<EB, 256, 0, stream>>>(dst, src, ew, degw, rowptr, fill, scsr, wcsr);

  // layer 1: hw0h = fp16(xh @ W0); h1h = fp16(relu(agg(hw0h) + b0))
  k_gemm_h<<<dim3(158, 8), 256, 0, stream>>>(xh, W0T, hw0h, 512, 512);
  k_agg2<512,_Float16><<<N_NODES, 128, 0, stream>>>(hw0h, b0, rowptr, scsr, wcsr, degw, h1h);
  // layer 2: hw1h = fp16(h1h @ W1); out = relu(agg(hw1h) + b1)
  k_gemm_h<<<dim3(158, 4), 256, 0, stream>>>(h1h, W1T, hw1h, 512, 256);
  k_agg2<256,float><<<N_NODES, 64, 0, stream>>>(hw1h, b1, rowptr, scsr, wcsr, degw, out);

  (void)in_sizes; (void)n_in; (void)out_size; (void)ws_size;
}